// Round 3
// baseline (388.776 us; speedup 1.0000x reference)
//
#include <hip/hip_runtime.h>
#include <hip/hip_bf16.h>

// B=8, S=1024, H=16, D=64, E=1024. I/O fp32; internal bf16 MFMA.
// attn = softmax over QUERY axis C (per key row c) of tril(K Q^T)/8.
// Two-pass: l_c = sum_{C<=c} exp(s_cC/8); V pre-scaled by 1/l_c (vscale);
// then z[C] = sum_{c>=C} exp(s_cC/8) * (v_c / l_c).
// R11: XCD-affinity block remap for both attn kernels (XCD = lin%8 owns 16
// heads -> per-XCD K/V working set ~4MB ~= L2, turning the 16.5x K/V
// re-reads from HBM misses (~900cy, R10: FETCH 74MB = 1.1KB/step) into L2
// hits). attn_av also gets a V ping-pong (prefetch distance 1, symmetric
// with K) so L2-hit latency is covered by the score chain. Work unchanged.
// attn_av: single-wave blocks, 32 C-rows, no barriers. GEMMs unchanged.

#define SEQ 1024
#define DH 64
#define NH 16
#define EMB 1024
#define SCALE 0.18033688011112042f  // 0.125 * log2(e)
#define PSTR 40                     // P row stride (u16), 80B = 16B-aligned

#define ZEROM 0
#define DIAGM 1
#define FULLM 2

typedef float f32x4 __attribute__((ext_vector_type(4)));
typedef __bf16 bf16x8 __attribute__((ext_vector_type(8)));
typedef unsigned short u16x8 __attribute__((ext_vector_type(8)));

__device__ __forceinline__ unsigned short f2bf(float f) {
  union { float f; unsigned int u; } v; v.f = f;
  unsigned int u = v.u;
  return (unsigned short)((u + 0x7fffu + ((u >> 16) & 1u)) >> 16);  // RNE
}
__device__ __forceinline__ unsigned short f2bf_fast(float f) {
  union { float f; unsigned int u; } v; v.f = f;
  return (unsigned short)((v.u + 0x8000u) >> 16);  // round-half-up (p>=0)
}
__device__ __forceinline__ float bf2f(unsigned short u) {
  union { unsigned int u; float f; } v; v.u = ((unsigned int)u) << 16; return v.f;
}

__device__ __forceinline__ u16x8 ld8_f32_bf16(const float* g) {
  const float4 a = *(const float4*)g;
  const float4 b = *(const float4*)(g + 4);
  u16x8 r;
  r[0] = f2bf(a.x); r[1] = f2bf(a.y); r[2] = f2bf(a.z); r[3] = f2bf(a.w);
  r[4] = f2bf(b.x); r[5] = f2bf(b.y); r[6] = f2bf(b.z); r[7] = f2bf(b.w);
  return r;
}

__device__ __forceinline__ void gl_lds16(const void* g, void* l) {
  __builtin_amdgcn_global_load_lds(
      (const __attribute__((address_space(1))) void*)g,
      (__attribute__((address_space(3))) void*)l, 16, 0, 0);
}

// ---------------- fp32 -> bf16 conversion of X and weights ----------------
__global__ __launch_bounds__(256) void cvt_bf16(
    const float* __restrict__ X, const float* __restrict__ Wk,
    const float* __restrict__ Wq, const float* __restrict__ Wv,
    const float* __restrict__ Wo,
    unsigned short* __restrict__ Xb, unsigned short* __restrict__ Wkb,
    unsigned short* __restrict__ Wqb, unsigned short* __restrict__ Wvb,
    unsigned short* __restrict__ Wob)
{
  const size_t i = ((size_t)blockIdx.x * 256 + threadIdx.x) * 8;
  const float* src; unsigned short* dst; size_t off;
  if (i < 8388608) { src = X; dst = Xb; off = i; }
  else {
    const size_t j = i - 8388608;
    const int sel = (int)(j >> 20); off = j & 1048575;
    src = (sel == 0) ? Wk : (sel == 1) ? Wq : (sel == 2) ? Wv : Wo;
    dst = (sel == 0) ? Wkb : (sel == 1) ? Wqb : (sel == 2) ? Wvb : Wob;
  }
  *(u16x8*)(dst + off) = ld8_f32_bf16(src + off);
}

// ---------------- GEMM core (BK=64, xor-swizzled LDS) ----------------
#define GEMM_BK64_BODY(Aptr, Bptr)                                              \
  f32x4 acc[4][4] = {};                                                         \
  const int srow = lane >> 3;                                                   \
  const int scol = (((lane & 7) ^ srow)) * 8;                                   \
  const unsigned short* Ag = (Aptr) + (size_t)(mt0 + wave * 32 + srow) * EMB + scol; \
  const unsigned short* Bg = (Bptr) + (size_t)(n0 + wave * 32 + srow) * EMB + scol;  \
  char* lA = (char*)As + wave * 4096;                                           \
  char* lB = (char*)Bs + wave * 4096;                                           \
  for (int k0 = 0; k0 < EMB; k0 += 64) {                                        \
    __syncthreads();                                                            \
    _Pragma("unroll")                                                           \
    for (int ch = 0; ch < 4; ch++) {                                            \
      gl_lds16(Ag + (size_t)ch * 8 * EMB + k0, lA + ch * 1024);                 \
      gl_lds16(Bg + (size_t)ch * 8 * EMB + k0, lB + ch * 1024);                 \
    }                                                                           \
    __syncthreads();                                                            \
    _Pragma("unroll")                                                           \
    for (int half = 0; half < 2; half++) {                                      \
      bf16x8 af[4], bfr[4];                                                     \
      _Pragma("unroll")                                                         \
      for (int t = 0; t < 4; t++) {                                             \
        const int ra = wm * 64 + t * 16 + fr;                                   \
        const int rb = wn * 64 + t * 16 + fr;                                   \
        af[t]  = *(const bf16x8*)&As[ra * 64 + (((half * 4 + quad) ^ (ra & 7)) * 8)]; \
        bfr[t] = *(const bf16x8*)&Bs[rb * 64 + (((half * 4 + quad) ^ (rb & 7)) * 8)]; \
      }                                                                         \
      _Pragma("unroll")                                                         \
      for (int i = 0; i < 4; i++)                                               \
        _Pragma("unroll")                                                       \
        for (int j = 0; j < 4; j++)                                             \
          acc[i][j] = __builtin_amdgcn_mfma_f32_16x16x32_bf16(af[i], bfr[j], acc[i][j], 0, 0, 0); \
    }                                                                           \
  }

// ---------------- GEMM: QKV projection ----------------
__global__ __launch_bounds__(256) void gemm_qkv(
    const unsigned short* __restrict__ X,
    const unsigned short* __restrict__ Wk,
    const unsigned short* __restrict__ Wq,
    const unsigned short* __restrict__ Wv,
    unsigned short* __restrict__ Kb,
    unsigned short* __restrict__ Qb,
    unsigned short* __restrict__ Vt)
{
  __shared__ __align__(16) unsigned short As[128 * 64];
  __shared__ __align__(16) unsigned short Bs[128 * 64];
  const int mt0 = blockIdx.x * 128;
  const int nt = blockIdx.y;
  const int sel = nt >> 3;
  const int n0 = (nt & 7) * 128;
  const unsigned short* W = (sel == 0) ? Wk : (sel == 1) ? Wq : Wv;

  const int tid = threadIdx.x;
  const int wave = tid >> 6, lane = tid & 63;
  const int wm = wave >> 1, wn = wave & 1;
  const int fr = lane & 15, quad = lane >> 4;

  GEMM_BK64_BODY(X, W)

  const int rl = quad * 4;
  if (sel < 2) {
    unsigned short* Dst = (sel == 0) ? Kb : Qb;
#pragma unroll
    for (int i = 0; i < 4; i++) {
      const int col = n0 + wn * 64 + i * 16 + fr;
      const int a = col >> 6, h = col & 63;
#pragma unroll
      for (int j = 0; j < 4; j++) {
        const int rowb = mt0 + wm * 64 + j * 16 + rl;
#pragma unroll
        for (int r = 0; r < 4; r++) {
          const int row = rowb + r;
          const int b = row >> 10, s = row & 1023;
          Dst[(size_t)((b * NH + a) * SEQ + s) * DH + h] = f2bf(acc[j][i][r]);
        }
      }
    }
  } else {
#pragma unroll
    for (int i = 0; i < 4; i++) {
      const int col = n0 + wn * 64 + i * 16 + fr;
      const int a = col >> 6, h = col & 63;
#pragma unroll
      for (int j = 0; j < 4; j++) {
        const int rowb = mt0 + wm * 64 + j * 16 + rl;
#pragma unroll
        for (int r = 0; r < 4; r++) {
          const int row = rowb + r;
          const int b = row >> 10, s = row & 1023;
          Vt[(size_t)((b * NH + a) * DH + h) * SEQ + s] = f2bf(acc[j][i][r]);
        }
      }
    }
  }
}

// ---------------- GEMM: output projection (bf16 in, fp32 out) ----------------
__global__ __launch_bounds__(256) void gemm_out(
    const unsigned short* __restrict__ Z,
    const unsigned short* __restrict__ Wo,
    float* __restrict__ Out)
{
  __shared__ __align__(16) unsigned short As[128 * 64];
  __shared__ __align__(16) unsigned short Bs[128 * 64];
  const int mt0 = blockIdx.x * 128;
  const int n0 = blockIdx.y * 128;

  const int tid = threadIdx.x;
  const int wave = tid >> 6, lane = tid & 63;
  const int wm = wave >> 1, wn = wave & 1;
  const int fr = lane & 15, quad = lane >> 4;

  GEMM_BK64_BODY(Z, Wo)

  const int rl = quad * 4;
#pragma unroll
  for (int i = 0; i < 4; i++) {
    const int col = n0 + wn * 64 + i * 16 + fr;
#pragma unroll
    for (int j = 0; j < 4; j++) {
      const int rowb = mt0 + wm * 64 + j * 16 + rl;
#pragma unroll
      for (int r = 0; r < 4; r++)
        Out[(size_t)(rowb + r) * EMB + col] = acc[j][i][r];
    }
  }
}

// ---------------- stats tile: accumulate exp into l4 ----------------
__device__ __forceinline__ void st_tile(
    const bf16x8* ka, const bf16x8* q, float* l4, int mode, int fr, int quad)
{
  f32x4 a = {0.f, 0.f, 0.f, 0.f};
  a = __builtin_amdgcn_mfma_f32_16x16x32_bf16(ka[0], q[0], a, 0, 0, 0);
  a = __builtin_amdgcn_mfma_f32_16x16x32_bf16(ka[1], q[1], a, 0, 0, 0);
#pragma unroll
  for (int i = 0; i < 4; i++) {
    const float e = exp2f(a[i] * SCALE);
    l4[i] += (mode == FULLM || fr <= quad * 4 + i) ? e : 0.f;
  }
}

// ---------------- Pass 1: l_c = sum_{C<=c} exp(s_cC/8) ----------------
// 4-wave blocks, 64 c-rows per block, waves split query tiles. XCD-affine
// block remap: XCD (lin%8) owns heads [16*xcd, 16*xcd+16) -> per-XCD
// working set (K block rows + streamed Q) ~fits 4MB L2. Heaviest chunk
// (jj=15) first within each head. grid 2048 blocks, 256 thr.
__global__ __launch_bounds__(256, 4) void attn_stats(
    const unsigned short* __restrict__ Kb, const unsigned short* __restrict__ Qb,
    float* __restrict__ Ls)
{
  __shared__ float lsum[4][16][64];  // [wave][s*4+i][lane] - conflict-free
  const int lin = blockIdx.x;
  const int xcd = lin & 7;
  const int idx = lin >> 3;          // 0..255 per XCD
  const int head = xcd * 16 + (idx >> 4);
  const int jj = 15 - (idx & 15);    // jj=15 (heaviest) first
  const int cw = jj * 64;
  const int tid = threadIdx.x;
  const int w = tid >> 6;
  const int lane = tid & 63;
  const int fr = lane & 15, quad = lane >> 4;
  const unsigned short* Kl = Kb + (size_t)head * (SEQ * DH) + (size_t)fr * DH + quad * 8;
  const unsigned short* Ql = Qb + (size_t)head * (SEQ * DH) + (size_t)fr * DH + quad * 8;

  // K fragments for this block's 64 c-rows (all waves load the same -> L1 hit)
  bf16x8 ka[4][2];
#pragma unroll
  for (int s = 0; s < 4; s++)
#pragma unroll
    for (int h = 0; h < 2; h++)
      ka[s][h] = *(const bf16x8*)(Kl + (size_t)(cw + s * 16) * DH + h * 32);

  float l[4][4] = {};

  // full region: 16-query tiles m = w + 4*i, i in [0, jj). All tiles FULL.
  if (jj > 0) {
    const unsigned short* q0p = Ql + (size_t)(w * 16) * DH;
    bf16x8 qc0 = *(const bf16x8*)(q0p);
    bf16x8 qc1 = *(const bf16x8*)(q0p + 32);
    for (int i = 0; i < jj; i++) {
      bf16x8 qn0 = qc0, qn1 = qc1;
      if (i + 1 < jj) {
        const unsigned short* qp = Ql + (size_t)((w + 4 * (i + 1)) * 16) * DH;
        qn0 = *(const bf16x8*)(qp);
        qn1 = *(const bf16x8*)(qp + 32);
      }
      bf16x8 qq[2] = {qc0, qc1};
#pragma unroll
      for (int s = 0; s < 4; s++)
        st_tile(ka[s], qq, l[s], FULLM, fr, quad);
      qc0 = qn0; qc1 = qn1;
    }
  }

  // diagonal 64x64 block: wave w covers queries [cw + w*16, cw + w*16 + 16)
  {
    const unsigned short* qp = Ql + (size_t)(cw + w * 16) * DH;
    bf16x8 qd[2];
    qd[0] = *(const bf16x8*)(qp);
    qd[1] = *(const bf16x8*)(qp + 32);
#pragma unroll
    for (int s = 0; s < 4; s++) {
      if (s >= w)
        st_tile(ka[s], qd, l[s], (s == w) ? DIAGM : FULLM, fr, quad);
    }
  }

  // cross-wave reduce, then shfl-over-fr reduce (wave 0)
#pragma unroll
  for (int s = 0; s < 4; s++)
#pragma unroll
    for (int i = 0; i < 4; i++)
      lsum[w][s * 4 + i][lane] = l[s][i];
  __syncthreads();
  if (w == 0) {
#pragma unroll
    for (int s = 0; s < 4; s++)
#pragma unroll
      for (int i = 0; i < 4; i++) {
        float v = lsum[0][s * 4 + i][lane] + lsum[1][s * 4 + i][lane]
                + lsum[2][s * 4 + i][lane] + lsum[3][s * 4 + i][lane];
        v += __shfl_xor(v, 1); v += __shfl_xor(v, 2);
        v += __shfl_xor(v, 4); v += __shfl_xor(v, 8);
        if (fr == 0) Ls[head * SEQ + cw + s * 16 + quad * 4 + i] = v;
      }
  }
}

// ---------------- V row-scale: Vt[head][h][s] *= 1/l_s ----------------
__global__ __launch_bounds__(256) void vscale(
    unsigned short* __restrict__ Vt, const float* __restrict__ Ls)
{
  const size_t i = ((size_t)blockIdx.x * 256 + threadIdx.x) * 8;  // < 8388608
  const int head = (int)(i >> 16);
  const int s = (int)(i & 1023);
  const float* lp = Ls + (head << 10) + s;
  const u16x8 v = *(const u16x8*)(Vt + i);
  const float4 la = *(const float4*)lp;
  const float4 lb = *(const float4*)(lp + 4);
  const float lv[8] = {la.x, la.y, la.z, la.w, lb.x, lb.y, lb.z, lb.w};
  u16x8 o;
#pragma unroll
  for (int j = 0; j < 8; j++)
    o[j] = f2bf(bf2f(v[j]) * __builtin_amdgcn_rcpf(lv[j]));
  *(u16x8*)(Vt + i) = o;
}

// ---------------- av score tile -> LDS (V pre-scaled) ----------------
__device__ __forceinline__ void av_tile(
    const bf16x8* ka, const bf16x8* bq,
    unsigned short* __restrict__ pw, int mode, int fr, int quad)
{
  if (mode == ZEROM) { *(uint2*)pw = make_uint2(0u, 0u); return; }
  f32x4 acc = {0.f, 0.f, 0.f, 0.f};
  acc = __builtin_amdgcn_mfma_f32_16x16x32_bf16(ka[0], bq[0], acc, 0, 0, 0);
  acc = __builtin_amdgcn_mfma_f32_16x16x32_bf16(ka[1], bq[1], acc, 0, 0, 0);
  unsigned short us[4];
#pragma unroll
  for (int i = 0; i < 4; i++) {
    float p = exp2f(acc[i] * SCALE);
    if (mode == DIAGM && (quad * 4 + i < fr)) p = 0.f;
    us[i] = f2bf_fast(p);
  }
  uint2 pk;
  pk.x = (unsigned)us[0] | ((unsigned)us[1] << 16);
  pk.y = (unsigned)us[2] | ((unsigned)us[3] << 16);
  *(uint2*)pw = pk;
}

// ---------------- Pass 2: z = P^T (V/l) ----------------
// Single-wave blocks, 32 C-rows/wave, no barriers. Ping-pong P in LDS;
// K AND V double-buffered in regs (prefetch distance 1). XCD-affine remap:
// XCD (lin%8) owns heads [16*xcd,16*xcd+16) -> per-XCD K+V working set
// 16*256KB ~= 4MB L2 -> re-reads are L2 hits. Chunk 0 (heaviest) first.
// grid 4096 blocks, 64 thr.
__global__ __launch_bounds__(64, 4) void attn_av(
    const unsigned short* __restrict__ Kb, const unsigned short* __restrict__ Qb,
    const unsigned short* __restrict__ Vt, unsigned short* __restrict__ Z)
{
  __shared__ __align__(16) unsigned short P[2][2][16 * PSTR];
  const int lin = blockIdx.x;
  const int xcd = lin & 7;
  const int idx = lin >> 3;          // 0..511 per XCD
  const int head = xcd * 16 + (idx >> 5);
  const int j = idx & 31;            // j=0 (heaviest) first
  const int Cw = j * 32;
  const int lane = threadIdx.x & 63;
  const int fr = lane & 15, quad = lane >> 4;
  const unsigned short* Kl = Kb + (size_t)head * (SEQ * DH) + (size_t)fr * DH + quad * 8;
  const unsigned short* Vl = Vt + (size_t)head * (SEQ * DH) + (size_t)fr * SEQ + quad * 8;

  // Q fragments for this block's 2 query tiles
  bf16x8 bq[2][2];
  {
    const unsigned short* Ql = Qb + (size_t)head * (SEQ * DH)
        + (size_t)(Cw + fr) * DH + quad * 8;
#pragma unroll
    for (int t = 0; t < 2; t++)
#pragma unroll
      for (int h = 0; h < 2; h++)
        bq[t][h] = *(const bf16x8*)(Ql + (size_t)(t * 16) * DH + h * 32);
  }

  f32x4 zacc[2][4] = {};
  bf16x8 kA0[2], kA1[2], kB0[2], kB1[2], vvA[4], vvB[4], pf[2];
  unsigned short* Pa = (unsigned short*)&P[0][0][0];
  unsigned short* Pb = (unsigned short*)&P[1][0][0];
  const int pwo = fr * PSTR + quad * 4;  // write col base (u16)
  const int pro = fr * PSTR + quad * 8;  // b128 read offset (u16)

  {  // prologue: scores keys [Cw, Cw+32) -> Pa (diagonal masks)
    bf16x8 k0[2], k1[2];
#pragma unroll
    for (int h = 0; h < 2; h++) {
      k0[h] = *(const bf16x8*)(Kl + (size_t)Cw * DH + h * 32);
      k1[h] = *(const bf16x8*)(Kl + (size_t)(Cw + 16) * DH + h * 32);
    }
    av_tile(k0, bq[0], Pa + pwo, DIAGM, fr, quad);
    av_tile(k0, bq[1], Pa + 16 * PSTR + pwo, ZEROM, fr, quad);
    av_tile(k1, bq[0], Pa + pwo + 16, FULLM, fr, quad);
    av_tile(k1, bq[1], Pa + 16 * PSTR + pwo + 16, DIAGM, fr, quad);
  }
  if (Cw + 32 < SEQ) {  // kA = K rows [Cw+32, Cw+64)
#pragma unroll
    for (int h = 0; h < 2; h++) {
      kA0[h] = *(const bf16x8*)(Kl + (size_t)(Cw + 32) * DH + h * 32);
      kA1[h] = *(const bf16x8*)(Kl + (size_t)(Cw + 48) * DH + h * 32);
    }
  }
#pragma unroll
  for (int n = 0; n < 4; n++)  // vvA = V cols [Cw, Cw+32)
    vvA[n] = *(const bf16x8*)(Vl + (size_t)(n * 16) * SEQ + Cw);

  int kb = Cw;
  if (j & 1) {  // odd trip count (32-j): peel one 32-key step
#pragma unroll
    for (int t = 0; t < 2; t++)
      pf[t] = *(const bf16x8*)(Pa + t * 16 * PSTR + pro);
    const bool has2 = (kb + 32 < SEQ);
    if (has2) {  // kb+96 <= SEQ always holds here (odd j <= 29)
#pragma unroll
      for (int n = 0; n < 4; n++)
        vvB[n] = *(const bf16x8*)(Vl + (size_t)(n * 16) * SEQ + (kb + 32));
#pragma unroll
      for (int h = 0; h < 2; h++) {
        kB0[h] = *(const bf16x8*)(Kl + (size_t)(kb + 64) * DH + h * 32);
        kB1[h] = *(const bf16x8*)(Kl + (size_t)(kb + 80) * DH + h * 32);
      }
      av_tile(kA0, bq[0], Pb + pwo, FULLM, fr, quad);
      av_tile(kA0, bq[1], Pb + 16 * PSTR + pwo, FULLM, fr, quad);
      av_tile(kA1, bq[0], Pb + pwo + 16, FULLM, fr, quad);
      av_tile(kA1, bq[1], Pb + 16 * PSTR + pwo + 16, FULLM, fr, quad);
    }
#pragma unroll
    for (int t = 0; t < 2; t++)
#pragma unroll
      for (int n = 0; n < 4; n++)
        zacc[t][n] = __builtin_amdgcn_mfma_f32_16x16x32_bf16(pf[t], vvA[n], zacc[t][n], 0, 0, 0);
    if (has2) {
      kA0[0] = kB0[0]; kA0[1] = kB0[1];
      kA1[0] = kB1[0]; kA1[1] = kB1[1];
#pragma unroll
      for (int n = 0; n < 4; n++) vvA[n] = vvB[n];
      unsigned short* tp = Pa; Pa = Pb; Pb = tp;
    }
    kb += 32;
  }

  for (; kb < SEQ; kb += 64) {  // even # of 32-key steps remain
    {  // step A: PV(Pa, vvA=V(kb)); scores(kA=keys [kb+32,kb+64)) -> Pb
#pragma unroll
      for (int t = 0; t < 2; t++)
        pf[t] = *(const bf16x8*)(Pa + t * 16 * PSTR + pro);
#pragma unroll
      for (int n = 0; n < 4; n++)  // next V (kb+32 < SEQ always here)
        vvB[n] = *(const bf16x8*)(Vl + (size_t)(n * 16) * SEQ + (kb + 32));
      if (kb + 64 < SEQ) {
#pragma unroll
        for (int h = 0; h < 2; h++) {
          kB0[h] = *(const bf16x8*)(Kl + (size_t)(kb + 64) * DH + h * 32);
          kB1[h] = *(const bf16x8*)(Kl + (size_t)(kb + 80) * DH + h * 32);
        }
      }
      av_tile(kA0, bq[0], Pb + pwo, FULLM, fr, quad);
      av_tile(kA0, bq[1], Pb + 16 * PSTR + pwo, FULLM, fr, quad);
      av_tile(kA1, bq[0], Pb + pwo + 16, FULLM, fr, quad);
      av_tile(kA1, bq[1], Pb + 16 * PSTR + pwo + 16, FULLM, fr, quad);
#pragma unroll
      for (int t = 0; t < 2; t++)
#pragma unroll
        for (int n = 0; n < 4; n++)
          zacc[t][n] = __builtin_amdgcn_mfma_f32_16x16x32_bf16(pf[t], vvA[n], zacc[t][n], 0, 0, 0);
    }
    {  // step B: PV(Pb, vvB=V(kb+32)); scores(kB=keys [kb+64,kb+96)) -> Pa
#pragma unroll
      for (int t = 0; t < 2; t++)
        pf[t] = *(const bf16x8*)(Pb + t * 16 * PSTR + pro);
      if (kb + 64 < SEQ) {
#pragma unroll
        for (int n = 0; n < 4; n++)  // next V
          vvA[n] = *(const bf16x8*)(Vl + (size_t)(n * 16) * SEQ + (kb + 64));
        if (kb + 96 < SEQ) {
#pragma unroll
          for (int h = 0; h < 2; h++) {
            kA0[h] = *(const bf16x8*)(Kl + (size_t)(kb + 96) * DH + h * 32);
            kA1[h] = *(const bf16x8*)(Kl + (size_t)(kb + 112) * DH + h * 32);
          }
        }
        av_tile(kB0, bq[0], Pa + pwo, FULLM, fr, quad);
        av_tile(kB0, bq[1], Pa + 16 * PSTR + pwo, FULLM, fr, quad);
        av_tile(kB1, bq[0], Pa + pwo + 16, FULLM, fr, quad);
        av_tile(kB1, bq[1], Pa + 16 * PSTR + pwo + 16, FULLM, fr, quad);
      }
#pragma unroll
      for (int t = 0; t < 2; t++)
#pragma unroll
        for (int n = 0; n < 4; n++)
          zacc[t][n] = __builtin_amdgcn_mfma_f32_16x16x32_bf16(pf[t], vvB[n], zacc[t][n], 0, 0, 0);
    }
  }

  const int b = head >> 4, a = head & 15;
#pragma unroll
  for (int t = 0; t < 2; t++)
#pragma unroll
    for (int n = 0; n < 4; n++)
#pragma unroll
      for (int i = 0; i < 4; i++) {
        const int C = Cw + t * 16 + quad * 4 + i;
        const int f = a * DH + n * 16 + fr;
        Z[((size_t)(b * SEQ + C) << 10) + f] = f2bf(zacc[t][n][i]);
      }
}

// ---------------- launch ----------------
extern "C" void kernel_launch(void* const* d_in, const int* in_sizes, int n_in,
                              void* d_out, int out_size, void* d_ws, size_t ws_size,
                              hipStream_t stream)
{
  const float* x  = (const float*)d_in[0];
  const float* wk = (const float*)d_in[1];
  const float* wq = (const float*)d_in[2];
  const float* wv = (const float*)d_in[3];
  const float* wo = (const float*)d_in[4];
  float* out = (float*)d_out;
  char* ws = (char*)d_ws;

  unsigned short* Xb  = (unsigned short*)(ws);            // 16 MB (aliased by Zb)
  unsigned short* Zb  = (unsigned short*)(ws);
  unsigned short* Kb  = (unsigned short*)(ws + 16777216);
  unsigned short* Qb  = (unsigned short*)(ws + 33554432);
  unsigned short* Vtb = (unsigned short*)(ws + 50331648);
  unsigned short* Wkb = (unsigned short*)(ws + 67108864);
  unsigned short* Wqb = (unsigned short*)(ws + 69206016);
  unsigned short* Wvb = (unsigned short*)(ws + 71303168);
  unsigned short* Wob = (unsigned short*)(ws + 73400320);
  float* Ls = (float*)(ws + 75497472);

  cvt_bf16<<<dim3(6144), 256, 0, stream>>>(x, wk, wq, wv, wo, Xb, Wkb, Wqb, Wvb, Wob);
  gemm_qkv<<<dim3(64, 24), 256, 0, stream>>>(Xb, Wkb, Wqb, Wvb, Kb, Qb, Vtb);
  attn_stats<<<dim3(2048), 256, 0, stream>>>(Kb, Qb, Ls);
  vscale<<<dim3(4096), 256, 0, stream>>>(Vtb, Ls);
  attn_av<<<dim3(4096), 64, 0, stream>>>(Kb, Qb, Vtb, Zb);
  gemm_out<<<dim3(64, 8), 256, 0, stream>>>(Zb, Wob, out);
}

// Round 4
// 295.478 us; speedup vs baseline: 1.3158x; 1.3158x over previous
//
#include <hip/hip_runtime.h>
#include <hip/hip_bf16.h>

// B=8, S=1024, H=16, D=64, E=1024. I/O fp32; internal bf16 MFMA.
// attn = softmax over QUERY axis C (per key row c) of tril(K Q^T)/8.
// Two-pass: l_c = sum_{C<=c} exp(s_cC/8); V pre-scaled by 1/l_c (vscale);
// then z[C] = sum_{c>=C} exp(s_cC/8) * (v_c / l_c).
// R12: attn kernels reverted to the round-0 (best-known, 266us-total) forms
// after three failed restructures (R9 barrier-lockstep, R10 small-chunk,
// R11 XCD remap -- all regressed with counter evidence). GEMMs rewritten
// with the verified 8-phase counted-vmcnt schedule (T2+T3+T4+T5):
// BM=128 BN=256 BK=64, 512 thr (8 waves 2Mx4N), LDS 96KB K-half staged,
// vmcnt(6) twice per K-tile (never 0 in loop), raw s_barrier (no drain),
// setprio around MFMA clusters, 2-way-free chunk^((row>>1)&3) swizzle.

#define SEQ 1024
#define DH 64
#define NH 16
#define EMB 1024
#define SCALE 0.18033688011112042f  // 0.125 * log2(e)
#define PSTR 40                     // P row stride (u16), 80B = 16B-aligned

#define ZEROM 0
#define DIAGM 1
#define FULLM 2

typedef float f32x4 __attribute__((ext_vector_type(4)));
typedef __bf16 bf16x8 __attribute__((ext_vector_type(8)));
typedef unsigned short u16x8 __attribute__((ext_vector_type(8)));

__device__ __forceinline__ unsigned short f2bf(float f) {
  union { float f; unsigned int u; } v; v.f = f;
  unsigned int u = v.u;
  return (unsigned short)((u + 0x7fffu + ((u >> 16) & 1u)) >> 16);  // RNE
}
__device__ __forceinline__ unsigned short f2bf_fast(float f) {
  union { float f; unsigned int u; } v; v.f = f;
  return (unsigned short)((v.u + 0x8000u) >> 16);  // round-half-up (p>=0)
}
__device__ __forceinline__ float bf2f(unsigned short u) {
  union { unsigned int u; float f; } v; v.u = ((unsigned int)u) << 16; return v.f;
}

__device__ __forceinline__ u16x8 ld8_f32_bf16(const float* g) {
  const float4 a = *(const float4*)g;
  const float4 b = *(const float4*)(g + 4);
  u16x8 r;
  r[0] = f2bf(a.x); r[1] = f2bf(a.y); r[2] = f2bf(a.z); r[3] = f2bf(a.w);
  r[4] = f2bf(b.x); r[5] = f2bf(b.y); r[6] = f2bf(b.z); r[7] = f2bf(b.w);
  return r;
}

__device__ __forceinline__ void gl_lds16(const void* g, void* l) {
  __builtin_amdgcn_global_load_lds(
      (const __attribute__((address_space(1))) void*)g,
      (__attribute__((address_space(3))) void*)l, 16, 0, 0);
}

// ---------------- fp32 -> bf16 conversion of X and weights ----------------
__global__ __launch_bounds__(256) void cvt_bf16(
    const float* __restrict__ X, const float* __restrict__ Wk,
    const float* __restrict__ Wq, const float* __restrict__ Wv,
    const float* __restrict__ Wo,
    unsigned short* __restrict__ Xb, unsigned short* __restrict__ Wkb,
    unsigned short* __restrict__ Wqb, unsigned short* __restrict__ Wvb,
    unsigned short* __restrict__ Wob)
{
  const size_t i = ((size_t)blockIdx.x * 256 + threadIdx.x) * 8;
  const float* src; unsigned short* dst; size_t off;
  if (i < 8388608) { src = X; dst = Xb; off = i; }
  else {
    const size_t j = i - 8388608;
    const int sel = (int)(j >> 20); off = j & 1048575;
    src = (sel == 0) ? Wk : (sel == 1) ? Wq : (sel == 2) ? Wv : Wo;
    dst = (sel == 0) ? Wkb : (sel == 1) ? Wqb : (sel == 2) ? Wvb : Wob;
  }
  *(u16x8*)(dst + off) = ld8_f32_bf16(src + off);
}

// ---------------- 8-phase GEMM core (BM=128, BN=256, BK=64) ----------------
// LDS: As[buf][kh][128][32], Bs[buf][kh][256][32] u16 = 96 KB.
// Swizzle: chunk' = chunk ^ ((row>>1)&3)  (2-way bank aliasing = free).
// Stage units per K-tile: A-kh (1 gl_lds/wave), B-kh (2 gl_lds/wave).
// Schedule: p0 stages A-kh1(t+1), p1 B-kh1(t+1), p2 A-kh0(t+2), p3 B-kh0(t+2).
// vmcnt(6) before p0 (tile entry) and before p2; tail: vmcnt(3)/vmcnt(0).

#define STAGE_A(bufi, kh, k0) {                                                 \
  const int rr_ = wave * 16 + (lane >> 2);                                      \
  gl_lds16(Ag + (size_t)rr_ * EMB + (k0) + (kh) * 32                            \
               + (((lane & 3) ^ ((rr_ >> 1) & 3)) << 3),                        \
           &As[bufi][kh][wave * 512]); }

#define STAGE_B(bufi, kh, k0) {                                                 \
  _Pragma("unroll")                                                             \
  for (int i_ = 0; i_ < 2; i_++) {                                              \
    const int rr_ = wave * 32 + i_ * 16 + (lane >> 2);                          \
    gl_lds16(Bg + (size_t)rr_ * EMB + (k0) + (kh) * 32                          \
                 + (((lane & 3) ^ ((rr_ >> 1) & 3)) << 3),                      \
             &Bs[bufi][kh][wave * 1024 + i_ * 512]); } }

#define RD(base, r) (*(const bf16x8*)&(base)[(r) * 32 + ((quad ^ (((r) >> 1) & 3)) << 3)])

#define MFMA8(i0, i1, x0, x1)                                                   \
  acc[i0][0] = __builtin_amdgcn_mfma_f32_16x16x32_bf16(x0, b0, acc[i0][0], 0, 0, 0); \
  acc[i1][0] = __builtin_amdgcn_mfma_f32_16x16x32_bf16(x1, b0, acc[i1][0], 0, 0, 0); \
  acc[i0][1] = __builtin_amdgcn_mfma_f32_16x16x32_bf16(x0, b1, acc[i0][1], 0, 0, 0); \
  acc[i1][1] = __builtin_amdgcn_mfma_f32_16x16x32_bf16(x1, b1, acc[i1][1], 0, 0, 0); \
  acc[i0][2] = __builtin_amdgcn_mfma_f32_16x16x32_bf16(x0, b2, acc[i0][2], 0, 0, 0); \
  acc[i1][2] = __builtin_amdgcn_mfma_f32_16x16x32_bf16(x1, b2, acc[i1][2], 0, 0, 0); \
  acc[i0][3] = __builtin_amdgcn_mfma_f32_16x16x32_bf16(x0, b3, acc[i0][3], 0, 0, 0); \
  acc[i1][3] = __builtin_amdgcn_mfma_f32_16x16x32_bf16(x1, b3, acc[i1][3], 0, 0, 0);

#define GEMM8P_CORE(Aptr, Bptr)                                                 \
  f32x4 acc[4][4] = {};                                                         \
  const int wave = tid >> 6, lane = tid & 63;                                   \
  const int wm = wave >> 2, wn = wave & 3;                                      \
  const int fr = lane & 15, quad = lane >> 4;                                   \
  const unsigned short* Ag = (Aptr) + (size_t)mt0 * EMB;                        \
  const unsigned short* Bg = (Bptr) + (size_t)n0 * EMB;                         \
  STAGE_A(0, 0, 0) STAGE_B(0, 0, 0) STAGE_A(0, 1, 0) STAGE_B(0, 1, 0)           \
  STAGE_A(1, 0, 64) STAGE_B(1, 0, 64)                                           \
  asm volatile("s_waitcnt vmcnt(6)" ::: "memory");                              \
  __builtin_amdgcn_s_barrier();                                                 \
  for (int t = 0; t < 15; ++t) {                                                \
    const int buf = t & 1;                                                      \
    const int k1 = (t + 1) * 64, k2 = (t + 2) * 64;                             \
    const unsigned short* A0p = &As[buf][0][0];                                 \
    const unsigned short* B0p = &Bs[buf][0][0];                                 \
    const unsigned short* A1p = &As[buf][1][0];                                 \
    const unsigned short* B1p = &Bs[buf][1][0];                                 \
    bf16x8 a0, a1, a2, a3, b0, b1, b2, b3;                                      \
    /* phase 0: kk0, m01 */                                                     \
    a0 = RD(A0p, wm * 64 + fr);      a1 = RD(A0p, wm * 64 + 16 + fr);           \
    b0 = RD(B0p, wn * 64 + fr);      b1 = RD(B0p, wn * 64 + 16 + fr);           \
    b2 = RD(B0p, wn * 64 + 32 + fr); b3 = RD(B0p, wn * 64 + 48 + fr);           \
    STAGE_A(buf ^ 1, 1, k1)                                                     \
    __builtin_amdgcn_s_barrier();                                               \
    __builtin_amdgcn_s_setprio(1);                                              \
    MFMA8(0, 1, a0, a1)                                                         \
    __builtin_amdgcn_s_setprio(0);                                              \
    __builtin_amdgcn_s_barrier();                                               \
    /* phase 1: kk0, m23 (B regs reused) */                                     \
    a2 = RD(A0p, wm * 64 + 32 + fr); a3 = RD(A0p, wm * 64 + 48 + fr);           \
    STAGE_B(buf ^ 1, 1, k1)                                                     \
    __builtin_amdgcn_s_barrier();                                               \
    __builtin_amdgcn_s_setprio(1);                                              \
    MFMA8(2, 3, a2, a3)                                                         \
    __builtin_amdgcn_s_setprio(0);                                              \
    asm volatile("s_waitcnt vmcnt(6)" ::: "memory");                            \
    __builtin_amdgcn_s_barrier();                                               \
    /* phase 2: kk1, m01 */                                                     \
    a0 = RD(A1p, wm * 64 + fr);      a1 = RD(A1p, wm * 64 + 16 + fr);           \
    b0 = RD(B1p, wn * 64 + fr);      b1 = RD(B1p, wn * 64 + 16 + fr);           \
    b2 = RD(B1p, wn * 64 + 32 + fr); b3 = RD(B1p, wn * 64 + 48 + fr);           \
    if (t < 14) { STAGE_A(buf, 0, k2) }                                         \
    __builtin_amdgcn_s_barrier();                                               \
    __builtin_amdgcn_s_setprio(1);                                              \
    MFMA8(0, 1, a0, a1)                                                         \
    __builtin_amdgcn_s_setprio(0);                                              \
    __builtin_amdgcn_s_barrier();                                               \
    /* phase 3: kk1, m23 */                                                     \
    a2 = RD(A1p, wm * 64 + 32 + fr); a3 = RD(A1p, wm * 64 + 48 + fr);           \
    if (t < 14) { STAGE_B(buf, 0, k2) }                                         \
    __builtin_amdgcn_s_barrier();                                               \
    __builtin_amdgcn_s_setprio(1);                                              \
    MFMA8(2, 3, a2, a3)                                                         \
    __builtin_amdgcn_s_setprio(0);                                              \
    if (t < 14) { asm volatile("s_waitcnt vmcnt(6)" ::: "memory"); }            \
    else        { asm volatile("s_waitcnt vmcnt(3)" ::: "memory"); }            \
    __builtin_amdgcn_s_barrier();                                               \
  }                                                                             \
  { /* peeled t = 15 (buf 1), no staging */                                     \
    const unsigned short* A0p = &As[1][0][0];                                   \
    const unsigned short* B0p = &Bs[1][0][0];                                   \
    const unsigned short* A1p = &As[1][1][0];                                   \
    const unsigned short* B1p = &Bs[1][1][0];                                   \
    bf16x8 a0, a1, a2, a3, b0, b1, b2, b3;                                      \
    a0 = RD(A0p, wm * 64 + fr);      a1 = RD(A0p, wm * 64 + 16 + fr);           \
    b0 = RD(B0p, wn * 64 + fr);      b1 = RD(B0p, wn * 64 + 16 + fr);           \
    b2 = RD(B0p, wn * 64 + 32 + fr); b3 = RD(B0p, wn * 64 + 48 + fr);           \
    MFMA8(0, 1, a0, a1)                                                         \
    a2 = RD(A0p, wm * 64 + 32 + fr); a3 = RD(A0p, wm * 64 + 48 + fr);           \
    MFMA8(2, 3, a2, a3)                                                         \
    asm volatile("s_waitcnt vmcnt(0)" ::: "memory");                            \
    __builtin_amdgcn_s_barrier();                                               \
    a0 = RD(A1p, wm * 64 + fr);      a1 = RD(A1p, wm * 64 + 16 + fr);           \
    b0 = RD(B1p, wn * 64 + fr);      b1 = RD(B1p, wn * 64 + 16 + fr);           \
    b2 = RD(B1p, wn * 64 + 32 + fr); b3 = RD(B1p, wn * 64 + 48 + fr);           \
    MFMA8(0, 1, a0, a1)                                                         \
    a2 = RD(A1p, wm * 64 + 32 + fr); a3 = RD(A1p, wm * 64 + 48 + fr);           \
    MFMA8(2, 3, a2, a3)                                                         \
  }

// ---------------- GEMM: QKV projection ----------------
__global__ __launch_bounds__(512) void gemm_qkv(
    const unsigned short* __restrict__ X,
    const unsigned short* __restrict__ Wk,
    const unsigned short* __restrict__ Wq,
    const unsigned short* __restrict__ Wv,
    unsigned short* __restrict__ Kb,
    unsigned short* __restrict__ Qb,
    unsigned short* __restrict__ Vt)
{
  __shared__ __align__(16) unsigned short As[2][2][128 * 32];
  __shared__ __align__(16) unsigned short Bs[2][2][256 * 32];
  const int mt0 = blockIdx.x * 128;
  const int by = blockIdx.y;
  const int sel = by >> 2;
  const int n0 = (by & 3) * 256;
  const unsigned short* W = (sel == 0) ? Wk : (sel == 1) ? Wq : Wv;
  const int tid = threadIdx.x;

  GEMM8P_CORE(X, W)

  const int rl = quad * 4;
  if (sel < 2) {
    unsigned short* Dst = (sel == 0) ? Kb : Qb;
#pragma unroll
    for (int i = 0; i < 4; i++) {
      const int col = n0 + wn * 64 + i * 16 + fr;
      const int a = col >> 6, h = col & 63;
#pragma unroll
      for (int j = 0; j < 4; j++) {
        const int rowb = mt0 + wm * 64 + j * 16 + rl;
#pragma unroll
        for (int r = 0; r < 4; r++) {
          const int row = rowb + r;
          const int b = row >> 10, s = row & 1023;
          Dst[(size_t)((b * NH + a) * SEQ + s) * DH + h] = f2bf(acc[j][i][r]);
        }
      }
    }
  } else {
#pragma unroll
    for (int i = 0; i < 4; i++) {
      const int col = n0 + wn * 64 + i * 16 + fr;
      const int a = col >> 6, h = col & 63;
#pragma unroll
      for (int j = 0; j < 4; j++) {
        const int rowb = mt0 + wm * 64 + j * 16 + rl;
#pragma unroll
        for (int r = 0; r < 4; r++) {
          const int row = rowb + r;
          const int b = row >> 10, s = row & 1023;
          Vt[(size_t)((b * NH + a) * DH + h) * SEQ + s] = f2bf(acc[j][i][r]);
        }
      }
    }
  }
}

// ---------------- GEMM: output projection (bf16 in, fp32 out) ----------------
__global__ __launch_bounds__(512) void gemm_out(
    const unsigned short* __restrict__ Z,
    const unsigned short* __restrict__ Wo,
    float* __restrict__ Out)
{
  __shared__ __align__(16) unsigned short As[2][2][128 * 32];
  __shared__ __align__(16) unsigned short Bs[2][2][256 * 32];
  const int mt0 = blockIdx.x * 128;
  const int n0 = blockIdx.y * 256;
  const int tid = threadIdx.x;

  GEMM8P_CORE(Z, Wo)

  const int rl = quad * 4;
#pragma unroll
  for (int i = 0; i < 4; i++) {
    const int col = n0 + wn * 64 + i * 16 + fr;
#pragma unroll
    for (int j = 0; j < 4; j++) {
      const int rowb = mt0 + wm * 64 + j * 16 + rl;
#pragma unroll
      for (int r = 0; r < 4; r++)
        Out[(size_t)(rowb + r) * EMB + col] = acc[j][i][r];
    }
  }
}

// ---------------- stats tile: accumulate exp into l4 ----------------
__device__ __forceinline__ void st_tile(
    const bf16x8* ka, const bf16x8* q, float* l4, int mode, int fr, int quad)
{
  f32x4 a = {0.f, 0.f, 0.f, 0.f};
  a = __builtin_amdgcn_mfma_f32_16x16x32_bf16(ka[0], q[0], a, 0, 0, 0);
  a = __builtin_amdgcn_mfma_f32_16x16x32_bf16(ka[1], q[1], a, 0, 0, 0);
#pragma unroll
  for (int i = 0; i < 4; i++) {
    const float e = exp2f(a[i] * SCALE);
    l4[i] += (mode == FULLM || fr <= quad * 4 + i) ? e : 0.f;
  }
}

// ---------------- Pass 1: l_c = sum_{C<=c} exp(s_cC/8) ----------------
// 64 c-rows per wave. grid (128 heads, 16 chunks), 64 thr. y=0 -> heaviest.
__global__ __launch_bounds__(64, 4) void attn_stats(
    const unsigned short* __restrict__ Kb, const unsigned short* __restrict__ Qb,
    float* __restrict__ Ls)
{
  const int head = blockIdx.x;
  const int j = 15 - (int)blockIdx.y;
  const int cw = j * 64;
  const int lane = threadIdx.x & 63;
  const int fr = lane & 15, quad = lane >> 4;
  const unsigned short* Kh = Kb + (size_t)head * (SEQ * DH);
  const unsigned short* Qh = Qb + (size_t)head * (SEQ * DH);
  const unsigned short* Kl = Kh + (size_t)fr * DH + quad * 8;
  const unsigned short* Ql = Qh + (size_t)fr * DH + quad * 8;

  bf16x8 ka[4][2];
#pragma unroll
  for (int s = 0; s < 4; s++)
#pragma unroll
    for (int h = 0; h < 2; h++)
      ka[s][h] = *(const bf16x8*)(Kl + (size_t)(cw + s * 16) * DH + h * 32);

  float l[4][4] = {};

  // main loop: full tiles, unroll-2 ping-pong (trip count 2j is even)
  bf16x8 qA0[2], qA1[2], qB0[2], qB1[2];
  if (cw > 0) {
#pragma unroll
    for (int h = 0; h < 2; h++) {
      qA0[h] = *(const bf16x8*)(Ql + h * 32);
      qA1[h] = *(const bf16x8*)(Ql + (size_t)16 * DH + h * 32);
    }
  }
  for (int Ct = 0; Ct < cw; Ct += 64) {
    {  // half A: queries [Ct, Ct+32)
      const int nq = Ct + 32;
      if (nq < cw) {
#pragma unroll
        for (int h = 0; h < 2; h++) {
          qB0[h] = *(const bf16x8*)(Ql + (size_t)nq * DH + h * 32);
          qB1[h] = *(const bf16x8*)(Ql + (size_t)(nq + 16) * DH + h * 32);
        }
      }
#pragma unroll
      for (int s = 0; s < 4; s++) {
        st_tile(ka[s], qA0, l[s], FULLM, fr, quad);
        st_tile(ka[s], qA1, l[s], FULLM, fr, quad);
      }
    }
    {  // half B: queries [Ct+32, Ct+64)
      const int cq = Ct + 32;
      if (cq < cw) {
        const int nq = cq + 32;
        if (nq < cw) {
#pragma unroll
          for (int h = 0; h < 2; h++) {
            qA0[h] = *(const bf16x8*)(Ql + (size_t)nq * DH + h * 32);
            qA1[h] = *(const bf16x8*)(Ql + (size_t)(nq + 16) * DH + h * 32);
          }
        }
#pragma unroll
        for (int s = 0; s < 4; s++) {
          st_tile(ka[s], qB0, l[s], FULLM, fr, quad);
          st_tile(ka[s], qB1, l[s], FULLM, fr, quad);
        }
      }
    }
  }

  {  // peeled Ct = cw (queries local [0,32))
    bf16x8 q0[2], q1[2];
#pragma unroll
    for (int h = 0; h < 2; h++) {
      q0[h] = *(const bf16x8*)(Ql + (size_t)cw * DH + h * 32);
      q1[h] = *(const bf16x8*)(Ql + (size_t)(cw + 16) * DH + h * 32);
    }
    st_tile(ka[0], q0, l[0], DIAGM, fr, quad);
    st_tile(ka[1], q0, l[1], FULLM, fr, quad);
    st_tile(ka[2], q0, l[2], FULLM, fr, quad);
    st_tile(ka[3], q0, l[3], FULLM, fr, quad);
    st_tile(ka[1], q1, l[1], DIAGM, fr, quad);
    st_tile(ka[2], q1, l[2], FULLM, fr, quad);
    st_tile(ka[3], q1, l[3], FULLM, fr, quad);
  }
  {  // peeled Ct = cw+32 (queries local [32,64))
    bf16x8 q0[2], q1[2];
#pragma unroll
    for (int h = 0; h < 2; h++) {
      q0[h] = *(const bf16x8*)(Ql + (size_t)(cw + 32) * DH + h * 32);
      q1[h] = *(const bf16x8*)(Ql + (size_t)(cw + 48) * DH + h * 32);
    }
    st_tile(ka[2], q0, l[2], DIAGM, fr, quad);
    st_tile(ka[3], q0, l[3], FULLM, fr, quad);
    st_tile(ka[3], q1, l[3], DIAGM, fr, quad);
  }

#pragma unroll
  for (int s = 0; s < 4; s++)
#pragma unroll
    for (int i = 0; i < 4; i++) {
      float v = l[s][i];
      v += __shfl_xor(v, 1); v += __shfl_xor(v, 2);
      v += __shfl_xor(v, 4); v += __shfl_xor(v, 8);
      if (fr == 0) Ls[head * SEQ + cw + s * 16 + quad * 4 + i] = v;
    }
}

// ---------------- V row-scale: Vt[head][h][s] *= 1/l_s ----------------
__global__ __launch_bounds__(256) void vscale(
    unsigned short* __restrict__ Vt, const float* __restrict__ Ls)
{
  const size_t i = ((size_t)blockIdx.x * 256 + threadIdx.x) * 8;  // < 8388608
  const int head = (int)(i >> 16);
  const int s = (int)(i & 1023);
  const float* lp = Ls + (head << 10) + s;
  const u16x8 v = *(const u16x8*)(Vt + i);
  const float4 la = *(const float4*)lp;
  const float4 lb = *(const float4*)(lp + 4);
  const float lv[8] = {la.x, la.y, la.z, la.w, lb.x, lb.y, lb.z, lb.w};
  u16x8 o;
#pragma unroll
  for (int j = 0; j < 8; j++)
    o[j] = f2bf(bf2f(v[j]) * __builtin_amdgcn_rcpf(lv[j]));
  *(u16x8*)(Vt + i) = o;
}

// ---------------- av score tile -> LDS (V pre-scaled) ----------------
__device__ __forceinline__ void av_tile(
    const bf16x8* ka, const bf16x8* bq,
    unsigned short* __restrict__ pw, int mode, int fr, int quad)
{
  if (mode == ZEROM) { *(uint2*)pw = make_uint2(0u, 0u); return; }
  f32x4 acc = {0.f, 0.f, 0.f, 0.f};
  acc = __builtin_amdgcn_mfma_f32_16x16x32_bf16(ka[0], bq[0], acc, 0, 0, 0);
  acc = __builtin_amdgcn_mfma_f32_16x16x32_bf16(ka[1], bq[1], acc, 0, 0, 0);
  unsigned short us[4];
#pragma unroll
  for (int i = 0; i < 4; i++) {
    float p = exp2f(acc[i] * SCALE);
    if (mode == DIAGM && (quad * 4 + i < fr)) p = 0.f;
    us[i] = f2bf_fast(p);
  }
  uint2 pk;
  pk.x = (unsigned)us[0] | ((unsigned)us[1] << 16);
  pk.y = (unsigned)us[2] | ((unsigned)us[3] << 16);
  *(uint2*)pw = pk;
}

// ---------------- Pass 2: z = P^T (V/l) ----------------
// 64 C-rows per wave, unroll-2 ping-pong (trip count 32-2j even), no barriers.
// grid (128 heads, 16 chunks), 64 thr. Chunk 0 heaviest, first.
__global__ __launch_bounds__(64, 2) void attn_av(
    const unsigned short* __restrict__ Kb, const unsigned short* __restrict__ Qb,
    const unsigned short* __restrict__ Vt, unsigned short* __restrict__ Z)
{
  __shared__ __align__(16) unsigned short P[2][4][16 * PSTR];
  const int head = blockIdx.x;
  const int lane = threadIdx.x & 63;
  const int fr = lane & 15, quad = lane >> 4;
  const unsigned short* Kh = Kb + (size_t)head * (SEQ * DH);
  const unsigned short* Qh = Qb + (size_t)head * (SEQ * DH);
  const unsigned short* Vh = Vt + (size_t)head * (SEQ * DH);
  const unsigned short* Kl = Kh + (size_t)fr * DH + quad * 8;
  const unsigned short* Ql = Qh + (size_t)fr * DH + quad * 8;
  const unsigned short* Vl = Vh + (size_t)fr * SEQ + quad * 8;
  const int Cw = blockIdx.y * 64;

  bf16x8 bq[4][2];
#pragma unroll
  for (int t = 0; t < 4; t++)
#pragma unroll
    for (int h = 0; h < 2; h++)
      bq[t][h] = *(const bf16x8*)(Ql + (size_t)(Cw + t * 16) * DH + h * 32);

  f32x4 zacc[4][4] = {};
  bf16x8 kA0[2], kA1[2], kB0[2], kB1[2], vA[4], vB[4];

  {  // prologue: scores(Cw) -> P[0]  (keys local [0,32))
    bf16x8 kp0[2], kp1[2];
#pragma unroll
    for (int h = 0; h < 2; h++) {
      kp0[h] = *(const bf16x8*)(Kl + (size_t)Cw * DH + h * 32);
      kp1[h] = *(const bf16x8*)(Kl + (size_t)(Cw + 16) * DH + h * 32);
    }
#pragma unroll
    for (int t = 0; t < 4; t++) {
      unsigned short* pw = &P[0][t][fr * PSTR + quad * 4];
      av_tile(kp0, bq[t], pw, (t == 0) ? DIAGM : ZEROM, fr, quad);
      av_tile(kp1, bq[t], pw + 16, (t == 0) ? FULLM : ((t == 1) ? DIAGM : ZEROM), fr, quad);
    }
  }
  if (Cw + 32 < SEQ) {  // K for first half-A scores
#pragma unroll
    for (int h = 0; h < 2; h++) {
      kA0[h] = *(const bf16x8*)(Kl + (size_t)(Cw + 32) * DH + h * 32);
      kA1[h] = *(const bf16x8*)(Kl + (size_t)(Cw + 48) * DH + h * 32);
    }
  }
#pragma unroll
  for (int n = 0; n < 4; n++)  // V(Cw)
    vA[n] = *(const bf16x8*)(Vl + (size_t)(n * 16) * SEQ + Cw);

  for (int cb = Cw; cb < SEQ; cb += 64) {
    {  // half A: PV(cb) from P[0]; scores(cb+32) -> P[1]
      const int nxt = cb + 32;
      if (nxt < SEQ) {
        if (cb + 64 < SEQ) {
#pragma unroll
          for (int h = 0; h < 2; h++) {
            kB0[h] = *(const bf16x8*)(Kl + (size_t)(cb + 64) * DH + h * 32);
            kB1[h] = *(const bf16x8*)(Kl + (size_t)(cb + 80) * DH + h * 32);
          }
        }
#pragma unroll
        for (int n = 0; n < 4; n++)
          vB[n] = *(const bf16x8*)(Vl + (size_t)(n * 16) * SEQ + nxt);
        const bool sp = (nxt == Cw + 32);  // keys local [32,64)
#pragma unroll
        for (int t = 0; t < 4; t++) {
          unsigned short* pw = &P[1][t][fr * PSTR + quad * 4];
          av_tile(kA0, bq[t], pw,
                  sp ? ((t < 2) ? FULLM : ((t == 2) ? DIAGM : ZEROM)) : FULLM, fr, quad);
          av_tile(kA1, bq[t], pw + 16,
                  sp ? ((t < 3) ? FULLM : DIAGM) : FULLM, fr, quad);
        }
      }
      bf16x8 pf[4];
#pragma unroll
      for (int t = 0; t < 4; t++)
        pf[t] = *(const bf16x8*)&P[0][t][fr * PSTR + quad * 8];
#pragma unroll
      for (int t = 0; t < 4; t++)
#pragma unroll
        for (int n = 0; n < 4; n++)
          zacc[t][n] = __builtin_amdgcn_mfma_f32_16x16x32_bf16(pf[t], vA[n], zacc[t][n], 0, 0, 0);
    }
    {  // half B: PV(cb+32) from P[1]; scores(cb+64) -> P[0]
      const int cb2 = cb + 32;  // always < SEQ (even trip count)
      const int nxt = cb2 + 32;
      if (nxt < SEQ) {
        if (cb2 + 64 < SEQ) {
#pragma unroll
          for (int h = 0; h < 2; h++) {
            kA0[h] = *(const bf16x8*)(Kl + (size_t)(cb2 + 64) * DH + h * 32);
            kA1[h] = *(const bf16x8*)(Kl + (size_t)(cb2 + 80) * DH + h * 32);
          }
        }
#pragma unroll
        for (int n = 0; n < 4; n++)
          vA[n] = *(const bf16x8*)(Vl + (size_t)(n * 16) * SEQ + nxt);
#pragma unroll
        for (int t = 0; t < 4; t++) {
          unsigned short* pw = &P[0][t][fr * PSTR + quad * 4];
          av_tile(kB0, bq[t], pw, FULLM, fr, quad);
          av_tile(kB1, bq[t], pw + 16, FULLM, fr, quad);
        }
      }
      bf16x8 pf[4];
#pragma unroll
      for (int t = 0; t < 4; t++)
        pf[t] = *(const bf16x8*)&P[1][t][fr * PSTR + quad * 8];
#pragma unroll
      for (int t = 0; t < 4; t++)
#pragma unroll
        for (int n = 0; n < 4; n++)
          zacc[t][n] = __builtin_amdgcn_mfma_f32_16x16x32_bf16(pf[t], vB[n], zacc[t][n], 0, 0, 0);
    }
  }

  const int b = head >> 4, a = head & 15;
#pragma unroll
  for (int t = 0; t < 4; t++)
#pragma unroll
    for (int n = 0; n < 4; n++)
#pragma unroll
      for (int i = 0; i < 4; i++) {
        const int C = Cw + t * 16 + quad * 4 + i;
        const int f = a * DH + n * 16 + fr;
        Z[((size_t)(b * SEQ + C) << 10) + f] = f2bf(zacc[t][n][i]);
      }
}

// ---------------- launch ----------------
extern "C" void kernel_launch(void* const* d_in, const int* in_sizes, int n_in,
                              void* d_out, int out_size, void* d_ws, size_t ws_size,
                              hipStream_t stream)
{
  const float* x  = (const float*)d_in[0];
  const float* wk = (const float*)d_in[1];
  const float* wq = (const float*)d_in[2];
  const float* wv = (const float*)d_in[3];
  const float* wo = (const float*)d_in[4];
  float* out = (float*)d_out;
  char* ws = (char*)d_ws;

  unsigned short* Xb  = (unsigned short*)(ws);            // 16 MB (aliased by Zb)
  unsigned short* Zb  = (unsigned short*)(ws);
  unsigned short* Kb  = (unsigned short*)(ws + 16777216);
  unsigned short* Qb  = (unsigned short*)(ws + 33554432);
  unsigned short* Vtb = (unsigned short*)(ws + 50331648);
  unsigned short* Wkb = (unsigned short*)(ws + 67108864);
  unsigned short* Wqb = (unsigned short*)(ws + 69206016);
  unsigned short* Wvb = (unsigned short*)(ws + 71303168);
  unsigned short* Wob = (unsigned short*)(ws + 73400320);
  float* Ls = (float*)(ws + 75497472);

  cvt_bf16<<<dim3(6144), 256, 0, stream>>>(x, wk, wq, wv, wo, Xb, Wkb, Wqb, Wvb, Wob);
  gemm_qkv<<<dim3(64, 12), 512, 0, stream>>>(Xb, Wkb, Wqb, Wvb, Kb, Qb, Vtb);
  attn_stats<<<dim3(128, 16), 64, 0, stream>>>(Kb, Qb, Ls);
  vscale<<<dim3(4096), 256, 0, stream>>>(Vtb, Ls);
  attn_av<<<dim3(128, 16), 64, 0, stream>>>(Kb, Qb, Vtb, Zb);
  gemm_out<<<dim3(64, 4), 512, 0, stream>>>(Zb, Wob, out);
}

// Round 5
// 285.666 us; speedup vs baseline: 1.3609x; 1.0343x over previous
//
#include <hip/hip_runtime.h>
#include <hip/hip_bf16.h>

// B=8, S=1024, H=16, D=64, E=1024. I/O fp32; internal bf16 MFMA.
// attn = softmax over QUERY axis C (per key row c) of tril(K Q^T)/8.
// Two-pass: l_c = sum_{C<=c} exp(s_cC/8); V pre-scaled by 1/l_c (vscale);
// then z[C] = sum_{c>=C} exp(s_cC/8) * (v_c / l_c).
// R13: GEMM restructured after R12 regression (kh1 prefetch lead was only
// ~2 phases < HBM latency; 8 barriers/tile). Now: full-tile TRIPLE buffer
// (144KB LDS), stage tile t+2 during tile t (lead ~2 tiles > 900cy), ONE
// vmcnt(6) + ONE s_barrier per K-tile (no drain until last tile). 3-bit
// row-XOR chunk swizzle (2-way, free). BM=128 BN=256 BK=64, 512 thr.
// attn kernels: round-0 known-good forms, untouched.

#define SEQ 1024
#define DH 64
#define NH 16
#define EMB 1024
#define SCALE 0.18033688011112042f  // 0.125 * log2(e)
#define PSTR 40                     // P row stride (u16), 80B = 16B-aligned

#define ZEROM 0
#define DIAGM 1
#define FULLM 2

typedef float f32x4 __attribute__((ext_vector_type(4)));
typedef __bf16 bf16x8 __attribute__((ext_vector_type(8)));
typedef unsigned short u16x8 __attribute__((ext_vector_type(8)));

__device__ __forceinline__ unsigned short f2bf(float f) {
  union { float f; unsigned int u; } v; v.f = f;
  unsigned int u = v.u;
  return (unsigned short)((u + 0x7fffu + ((u >> 16) & 1u)) >> 16);  // RNE
}
__device__ __forceinline__ unsigned short f2bf_fast(float f) {
  union { float f; unsigned int u; } v; v.f = f;
  return (unsigned short)((v.u + 0x8000u) >> 16);  // round-half-up (p>=0)
}
__device__ __forceinline__ float bf2f(unsigned short u) {
  union { unsigned int u; float f; } v; v.u = ((unsigned int)u) << 16; return v.f;
}

__device__ __forceinline__ u16x8 ld8_f32_bf16(const float* g) {
  const float4 a = *(const float4*)g;
  const float4 b = *(const float4*)(g + 4);
  u16x8 r;
  r[0] = f2bf(a.x); r[1] = f2bf(a.y); r[2] = f2bf(a.z); r[3] = f2bf(a.w);
  r[4] = f2bf(b.x); r[5] = f2bf(b.y); r[6] = f2bf(b.z); r[7] = f2bf(b.w);
  return r;
}

__device__ __forceinline__ void gl_lds16(const void* g, void* l) {
  __builtin_amdgcn_global_load_lds(
      (const __attribute__((address_space(1))) void*)g,
      (__attribute__((address_space(3))) void*)l, 16, 0, 0);
}

// ---------------- fp32 -> bf16 conversion of X and weights ----------------
__global__ __launch_bounds__(256) void cvt_bf16(
    const float* __restrict__ X, const float* __restrict__ Wk,
    const float* __restrict__ Wq, const float* __restrict__ Wv,
    const float* __restrict__ Wo,
    unsigned short* __restrict__ Xb, unsigned short* __restrict__ Wkb,
    unsigned short* __restrict__ Wqb, unsigned short* __restrict__ Wvb,
    unsigned short* __restrict__ Wob)
{
  const size_t i = ((size_t)blockIdx.x * 256 + threadIdx.x) * 8;
  const float* src; unsigned short* dst; size_t off;
  if (i < 8388608) { src = X; dst = Xb; off = i; }
  else {
    const size_t j = i - 8388608;
    const int sel = (int)(j >> 20); off = j & 1048575;
    src = (sel == 0) ? Wk : (sel == 1) ? Wq : (sel == 2) ? Wv : Wo;
    dst = (sel == 0) ? Wkb : (sel == 1) ? Wqb : (sel == 2) ? Wvb : Wob;
  }
  *(u16x8*)(dst + off) = ld8_f32_bf16(src + off);
}

// ------- triple-buffered GEMM core (BM=128, BN=256, BK=64, 512 thr) -------
// LDS: As[3][128*64], Bs[3][256*64] u16 = 144 KB. Rows 128B (64 u16),
// 8 chunks of 8 u16; swizzle chunk' = chunk ^ ((row>>1)&7) (2-way, free).
// Stage tile t+2 during tile t (6 gl_lds units/wave/tile: A x2, B x4).
// Entry of tile t: vmcnt(6) (own units for t landed; t+1's in flight),
// then ONE s_barrier. No other barriers; no drain except last tile.

#define SWZ(r) (((r) >> 1) & 7)

#define STAGE_A3(bufi, k0) {                                                    \
  _Pragma("unroll")                                                             \
  for (int c_ = 0; c_ < 2; c_++) {                                              \
    const int rr_ = wave * 16 + c_ * 8 + (lane >> 3);                           \
    gl_lds16(Ag + (size_t)rr_ * EMB + (k0)                                      \
                 + (((lane & 7) ^ SWZ(rr_)) << 3),                              \
             &As[bufi][(wave * 16 + c_ * 8) * 64]);                             \
  } }

#define STAGE_B3(bufi, k0, c0, c1) {                                            \
  _Pragma("unroll")                                                             \
  for (int c_ = (c0); c_ <= (c1); c_++) {                                       \
    const int rr_ = wave * 32 + c_ * 8 + (lane >> 3);                           \
    gl_lds16(Bg + (size_t)rr_ * EMB + (k0)                                      \
                 + (((lane & 7) ^ SWZ(rr_)) << 3),                              \
             &Bs[bufi][(wave * 32 + c_ * 8) * 64]);                             \
  } }

#define RD3(base, r, kk) \
  (*(const bf16x8*)&(base)[(r) * 64 + ((((kk) * 4 + quad) ^ SWZ(r)) << 3)])

#define MFMA8(i0, i1, x0, x1)                                                   \
  acc[i0][0] = __builtin_amdgcn_mfma_f32_16x16x32_bf16(x0, b0, acc[i0][0], 0, 0, 0); \
  acc[i1][0] = __builtin_amdgcn_mfma_f32_16x16x32_bf16(x1, b0, acc[i1][0], 0, 0, 0); \
  acc[i0][1] = __builtin_amdgcn_mfma_f32_16x16x32_bf16(x0, b1, acc[i0][1], 0, 0, 0); \
  acc[i1][1] = __builtin_amdgcn_mfma_f32_16x16x32_bf16(x1, b1, acc[i1][1], 0, 0, 0); \
  acc[i0][2] = __builtin_amdgcn_mfma_f32_16x16x32_bf16(x0, b2, acc[i0][2], 0, 0, 0); \
  acc[i1][2] = __builtin_amdgcn_mfma_f32_16x16x32_bf16(x1, b2, acc[i1][2], 0, 0, 0); \
  acc[i0][3] = __builtin_amdgcn_mfma_f32_16x16x32_bf16(x0, b3, acc[i0][3], 0, 0, 0); \
  acc[i1][3] = __builtin_amdgcn_mfma_f32_16x16x32_bf16(x1, b3, acc[i1][3], 0, 0, 0);

#define GEMM3B_CORE(Aptr, Bptr)                                                 \
  f32x4 acc[4][4] = {};                                                         \
  const int wave = tid >> 6, lane = tid & 63;                                   \
  const int wm = wave >> 2, wn = wave & 3;                                      \
  const int fr = lane & 15, quad = lane >> 4;                                   \
  const unsigned short* Ag = (Aptr) + (size_t)mt0 * EMB;                        \
  const unsigned short* Bg = (Bptr) + (size_t)n0 * EMB;                         \
  STAGE_A3(0, 0) STAGE_B3(0, 0, 0, 3)        /* tile 0: 6 units */              \
  STAGE_A3(1, 64) STAGE_B3(1, 64, 0, 3)      /* tile 1: 6 units */              \
  for (int t = 0; t < 16; ++t) {                                                \
    const int bc = t % 3, bs = (t + 2) % 3;                                     \
    const int k2 = (t + 2) * 64;                                                \
    if (t < 15) { asm volatile("s_waitcnt vmcnt(6)" ::: "memory"); }            \
    else        { asm volatile("s_waitcnt vmcnt(0)" ::: "memory"); }            \
    __builtin_amdgcn_s_barrier();                                               \
    const unsigned short* Ap = &As[bc][0];                                      \
    const unsigned short* Bp = &Bs[bc][0];                                      \
    bf16x8 a0, a1, a2, a3, b0, b1, b2, b3;                                      \
    if (t < 14) { STAGE_A3(bs, k2) }                                            \
    /* cluster 0: kk=0, rows m0/m1 */                                           \
    a0 = RD3(Ap, wm * 64 + fr, 0);       a1 = RD3(Ap, wm * 64 + 16 + fr, 0);    \
    b0 = RD3(Bp, wn * 64 + fr, 0);       b1 = RD3(Bp, wn * 64 + 16 + fr, 0);    \
    b2 = RD3(Bp, wn * 64 + 32 + fr, 0);  b3 = RD3(Bp, wn * 64 + 48 + fr, 0);    \
    __builtin_amdgcn_s_setprio(1);                                              \
    MFMA8(0, 1, a0, a1)                                                         \
    __builtin_amdgcn_s_setprio(0);                                              \
    if (t < 14) { STAGE_B3(bs, k2, 0, 1) }                                      \
    /* cluster 1: kk=0, rows m2/m3 */                                           \
    a2 = RD3(Ap, wm * 64 + 32 + fr, 0);  a3 = RD3(Ap, wm * 64 + 48 + fr, 0);    \
    __builtin_amdgcn_s_setprio(1);                                              \
    MFMA8(2, 3, a2, a3)                                                         \
    __builtin_amdgcn_s_setprio(0);                                              \
    if (t < 14) { STAGE_B3(bs, k2, 2, 3) }                                      \
    /* cluster 2: kk=1, rows m0/m1 */                                           \
    a0 = RD3(Ap, wm * 64 + fr, 1);       a1 = RD3(Ap, wm * 64 + 16 + fr, 1);    \
    b0 = RD3(Bp, wn * 64 + fr, 1);       b1 = RD3(Bp, wn * 64 + 16 + fr, 1);    \
    b2 = RD3(Bp, wn * 64 + 32 + fr, 1);  b3 = RD3(Bp, wn * 64 + 48 + fr, 1);    \
    __builtin_amdgcn_s_setprio(1);                                              \
    MFMA8(0, 1, a0, a1)                                                         \
    __builtin_amdgcn_s_setprio(0);                                              \
    /* cluster 3: kk=1, rows m2/m3 */                                           \
    a2 = RD3(Ap, wm * 64 + 32 + fr, 1);  a3 = RD3(Ap, wm * 64 + 48 + fr, 1);    \
    __builtin_amdgcn_s_setprio(1);                                              \
    MFMA8(2, 3, a2, a3)                                                         \
    __builtin_amdgcn_s_setprio(0);                                              \
  }

// ---------------- GEMM: QKV projection ----------------
__global__ __launch_bounds__(512) void gemm_qkv(
    const unsigned short* __restrict__ X,
    const unsigned short* __restrict__ Wk,
    const unsigned short* __restrict__ Wq,
    const unsigned short* __restrict__ Wv,
    unsigned short* __restrict__ Kb,
    unsigned short* __restrict__ Qb,
    unsigned short* __restrict__ Vt)
{
  __shared__ __align__(16) unsigned short As[3][128 * 64];
  __shared__ __align__(16) unsigned short Bs[3][256 * 64];
  const int mt0 = blockIdx.x * 128;
  const int by = blockIdx.y;
  const int sel = by >> 2;
  const int n0 = (by & 3) * 256;
  const unsigned short* W = (sel == 0) ? Wk : (sel == 1) ? Wq : Wv;
  const int tid = threadIdx.x;

  GEMM3B_CORE(X, W)

  const int rl = quad * 4;
  if (sel < 2) {
    unsigned short* Dst = (sel == 0) ? Kb : Qb;
#pragma unroll
    for (int i = 0; i < 4; i++) {
      const int col = n0 + wn * 64 + i * 16 + fr;
      const int a = col >> 6, h = col & 63;
#pragma unroll
      for (int j = 0; j < 4; j++) {
        const int rowb = mt0 + wm * 64 + j * 16 + rl;
#pragma unroll
        for (int r = 0; r < 4; r++) {
          const int row = rowb + r;
          const int b = row >> 10, s = row & 1023;
          Dst[(size_t)((b * NH + a) * SEQ + s) * DH + h] = f2bf(acc[j][i][r]);
        }
      }
    }
  } else {
#pragma unroll
    for (int i = 0; i < 4; i++) {
      const int col = n0 + wn * 64 + i * 16 + fr;
      const int a = col >> 6, h = col & 63;
#pragma unroll
      for (int j = 0; j < 4; j++) {
        const int rowb = mt0 + wm * 64 + j * 16 + rl;
#pragma unroll
        for (int r = 0; r < 4; r++) {
          const int row = rowb + r;
          const int b = row >> 10, s = row & 1023;
          Vt[(size_t)((b * NH + a) * DH + h) * SEQ + s] = f2bf(acc[j][i][r]);
        }
      }
    }
  }
}

// ---------------- GEMM: output projection (bf16 in, fp32 out) ----------------
__global__ __launch_bounds__(512) void gemm_out(
    const unsigned short* __restrict__ Z,
    const unsigned short* __restrict__ Wo,
    float* __restrict__ Out)
{
  __shared__ __align__(16) unsigned short As[3][128 * 64];
  __shared__ __align__(16) unsigned short Bs[3][256 * 64];
  const int mt0 = blockIdx.x * 128;
  const int n0 = blockIdx.y * 256;
  const int tid = threadIdx.x;

  GEMM3B_CORE(Z, Wo)

  const int rl = quad * 4;
#pragma unroll
  for (int i = 0; i < 4; i++) {
    const int col = n0 + wn * 64 + i * 16 + fr;
#pragma unroll
    for (int j = 0; j < 4; j++) {
      const int rowb = mt0 + wm * 64 + j * 16 + rl;
#pragma unroll
      for (int r = 0; r < 4; r++)
        Out[(size_t)(rowb + r) * EMB + col] = acc[j][i][r];
    }
  }
}

// ---------------- stats tile: accumulate exp into l4 ----------------
__device__ __forceinline__ void st_tile(
    const bf16x8* ka, const bf16x8* q, float* l4, int mode, int fr, int quad)
{
  f32x4 a = {0.f, 0.f, 0.f, 0.f};
  a = __builtin_amdgcn_mfma_f32_16x16x32_bf16(ka[0], q[0], a, 0, 0, 0);
  a = __builtin_amdgcn_mfma_f32_16x16x32_bf16(ka[1], q[1], a, 0, 0, 0);
#pragma unroll
  for (int i = 0; i < 4; i++) {
    const float e = exp2f(a[i] * SCALE);
    l4[i] += (mode == FULLM || fr <= quad * 4 + i) ? e : 0.f;
  }
}

// ---------------- Pass 1: l_c = sum_{C<=c} exp(s_cC/8) ----------------
// 64 c-rows per wave. grid (128 heads, 16 chunks), 64 thr. y=0 -> heaviest.
__global__ __launch_bounds__(64, 4) void attn_stats(
    const unsigned short* __restrict__ Kb, const unsigned short* __restrict__ Qb,
    float* __restrict__ Ls)
{
  const int head = blockIdx.x;
  const int j = 15 - (int)blockIdx.y;
  const int cw = j * 64;
  const int lane = threadIdx.x & 63;
  const int fr = lane & 15, quad = lane >> 4;
  const unsigned short* Kh = Kb + (size_t)head * (SEQ * DH);
  const unsigned short* Qh = Qb + (size_t)head * (SEQ * DH);
  const unsigned short* Kl = Kh + (size_t)fr * DH + quad * 8;
  const unsigned short* Ql = Qh + (size_t)fr * DH + quad * 8;

  bf16x8 ka[4][2];
#pragma unroll
  for (int s = 0; s < 4; s++)
#pragma unroll
    for (int h = 0; h < 2; h++)
      ka[s][h] = *(const bf16x8*)(Kl + (size_t)(cw + s * 16) * DH + h * 32);

  float l[4][4] = {};

  // main loop: full tiles, unroll-2 ping-pong (trip count 2j is even)
  bf16x8 qA0[2], qA1[2], qB0[2], qB1[2];
  if (cw > 0) {
#pragma unroll
    for (int h = 0; h < 2; h++) {
      qA0[h] = *(const bf16x8*)(Ql + h * 32);
      qA1[h] = *(const bf16x8*)(Ql + (size_t)16 * DH + h * 32);
    }
  }
  for (int Ct = 0; Ct < cw; Ct += 64) {
    {  // half A: queries [Ct, Ct+32)
      const int nq = Ct + 32;
      if (nq < cw) {
#pragma unroll
        for (int h = 0; h < 2; h++) {
          qB0[h] = *(const bf16x8*)(Ql + (size_t)nq * DH + h * 32);
          qB1[h] = *(const bf16x8*)(Ql + (size_t)(nq + 16) * DH + h * 32);
        }
      }
#pragma unroll
      for (int s = 0; s < 4; s++) {
        st_tile(ka[s], qA0, l[s], FULLM, fr, quad);
        st_tile(ka[s], qA1, l[s], FULLM, fr, quad);
      }
    }
    {  // half B: queries [Ct+32, Ct+64)
      const int cq = Ct + 32;
      if (cq < cw) {
        const int nq = cq + 32;
        if (nq < cw) {
#pragma unroll
          for (int h = 0; h < 2; h++) {
            qA0[h] = *(const bf16x8*)(Ql + (size_t)nq * DH + h * 32);
            qA1[h] = *(const bf16x8*)(Ql + (size_t)(nq + 16) * DH + h * 32);
          }
        }
#pragma unroll
        for (int s = 0; s < 4; s++) {
          st_tile(ka[s], qB0, l[s], FULLM, fr, quad);
          st_tile(ka[s], qB1, l[s], FULLM, fr, quad);
        }
      }
    }
  }

  {  // peeled Ct = cw (queries local [0,32))
    bf16x8 q0[2], q1[2];
#pragma unroll
    for (int h = 0; h < 2; h++) {
      q0[h] = *(const bf16x8*)(Ql + (size_t)cw * DH + h * 32);
      q1[h] = *(const bf16x8*)(Ql + (size_t)(cw + 16) * DH + h * 32);
    }
    st_tile(ka[0], q0, l[0], DIAGM, fr, quad);
    st_tile(ka[1], q0, l[1], FULLM, fr, quad);
    st_tile(ka[2], q0, l[2], FULLM, fr, quad);
    st_tile(ka[3], q0, l[3], FULLM, fr, quad);
    st_tile(ka[1], q1, l[1], DIAGM, fr, quad);
    st_tile(ka[2], q1, l[2], FULLM, fr, quad);
    st_tile(ka[3], q1, l[3], FULLM, fr, quad);
  }
  {  // peeled Ct = cw+32 (queries local [32,64))
    bf16x8 q0[2], q1[2];
#pragma unroll
    for (int h = 0; h < 2; h++) {
      q0[h] = *(const bf16x8*)(Ql + (size_t)(cw + 32) * DH + h * 32);
      q1[h] = *(const bf16x8*)(Ql + (size_t)(cw + 48) * DH + h * 32);
    }
    st_tile(ka[2], q0, l[2], DIAGM, fr, quad);
    st_tile(ka[3], q0, l[3], FULLM, fr, quad);
    st_tile(ka[3], q1, l[3], DIAGM, fr, quad);
  }

#pragma unroll
  for (int s = 0; s < 4; s++)
#pragma unroll
    for (int i = 0; i < 4; i++) {
      float v = l[s][i];
      v += __shfl_xor(v, 1); v += __shfl_xor(v, 2);
      v += __shfl_xor(v, 4); v += __shfl_xor(v, 8);
      if (fr == 0) Ls[head * SEQ + cw + s * 16 + quad * 4 + i] = v;
    }
}

// ---------------- V row-scale: Vt[head][h][s] *= 1/l_s ----------------
__global__ __launch_bounds__(256) void vscale(
    unsigned short* __restrict__ Vt, const float* __restrict__ Ls)
{
  const size_t i = ((size_t)blockIdx.x * 256 + threadIdx.x) * 8;  // < 8388608
  const int head = (int)(i >> 16);
  const int s = (int)(i & 1023);
  const float* lp = Ls + (head << 10) + s;
  const u16x8 v = *(const u16x8*)(Vt + i);
  const float4 la = *(const float4*)lp;
  const float4 lb = *(const float4*)(lp + 4);
  const float lv[8] = {la.x, la.y, la.z, la.w, lb.x, lb.y, lb.z, lb.w};
  u16x8 o;
#pragma unroll
  for (int j = 0; j < 8; j++)
    o[j] = f2bf(bf2f(v[j]) * __builtin_amdgcn_rcpf(lv[j]));
  *(u16x8*)(Vt + i) = o;
}

// ---------------- av score tile -> LDS (V pre-scaled) ----------------
__device__ __forceinline__ void av_tile(
    const bf16x8* ka, const bf16x8* bq,
    unsigned short* __restrict__ pw, int mode, int fr, int quad)
{
  if (mode == ZEROM) { *(uint2*)pw = make_uint2(0u, 0u); return; }
  f32x4 acc = {0.f, 0.f, 0.f, 0.f};
  acc = __builtin_amdgcn_mfma_f32_16x16x32_bf16(ka[0], bq[0], acc, 0, 0, 0);
  acc = __builtin_amdgcn_mfma_f32_16x16x32_bf16(ka[1], bq[1], acc, 0, 0, 0);
  unsigned short us[4];
#pragma unroll
  for (int i = 0; i < 4; i++) {
    float p = exp2f(acc[i] * SCALE);
    if (mode == DIAGM && (quad * 4 + i < fr)) p = 0.f;
    us[i] = f2bf_fast(p);
  }
  uint2 pk;
  pk.x = (unsigned)us[0] | ((unsigned)us[1] << 16);
  pk.y = (unsigned)us[2] | ((unsigned)us[3] << 16);
  *(uint2*)pw = pk;
}

// ---------------- Pass 2: z = P^T (V/l) ----------------
// 64 C-rows per wave, unroll-2 ping-pong (trip count 32-2j even), no barriers.
// grid (128 heads, 16 chunks), 64 thr. Chunk 0 heaviest, first.
__global__ __launch_bounds__(64, 2) void attn_av(
    const unsigned short* __restrict__ Kb, const unsigned short* __restrict__ Qb,
    const unsigned short* __restrict__ Vt, unsigned short* __restrict__ Z)
{
  __shared__ __align__(16) unsigned short P[2][4][16 * PSTR];
  const int head = blockIdx.x;
  const int lane = threadIdx.x & 63;
  const int fr = lane & 15, quad = lane >> 4;
  const unsigned short* Kh = Kb + (size_t)head * (SEQ * DH);
  const unsigned short* Qh = Qb + (size_t)head * (SEQ * DH);
  const unsigned short* Vh = Vt + (size_t)head * (SEQ * DH);
  const unsigned short* Kl = Kh + (size_t)fr * DH + quad * 8;
  const unsigned short* Ql = Qh + (size_t)fr * DH + quad * 8;
  const unsigned short* Vl = Vh + (size_t)fr * SEQ + quad * 8;
  const int Cw = blockIdx.y * 64;

  bf16x8 bq[4][2];
#pragma unroll
  for (int t = 0; t < 4; t++)
#pragma unroll
    for (int h = 0; h < 2; h++)
      bq[t][h] = *(const bf16x8*)(Ql + (size_t)(Cw + t * 16) * DH + h * 32);

  f32x4 zacc[4][4] = {};
  bf16x8 kA0[2], kA1[2], kB0[2], kB1[2], vA[4], vB[4];

  {  // prologue: scores(Cw) -> P[0]  (keys local [0,32))
    bf16x8 kp0[2], kp1[2];
#pragma unroll
    for (int h = 0; h < 2; h++) {
      kp0[h] = *(const bf16x8*)(Kl + (size_t)Cw * DH + h * 32);
      kp1[h] = *(const bf16x8*)(Kl + (size_t)(Cw + 16) * DH + h * 32);
    }
#pragma unroll
    for (int t = 0; t < 4; t++) {
      unsigned short* pw = &P[0][t][fr * PSTR + quad * 4];
      av_tile(kp0, bq[t], pw, (t == 0) ? DIAGM : ZEROM, fr, quad);
      av_tile(kp1, bq[t], pw + 16, (t == 0) ? FULLM : ((t == 1) ? DIAGM : ZEROM), fr, quad);
    }
  }
  if (Cw + 32 < SEQ) {  // K for first half-A scores
#pragma unroll
    for (int h = 0; h < 2; h++) {
      kA0[h] = *(const bf16x8*)(Kl + (size_t)(Cw + 32) * DH + h * 32);
      kA1[h] = *(const bf16x8*)(Kl + (size_t)(Cw + 48) * DH + h * 32);
    }
  }
#pragma unroll
  for (int n = 0; n < 4; n++)  // V(Cw)
    vA[n] = *(const bf16x8*)(Vl + (size_t)(n * 16) * SEQ + Cw);

  for (int cb = Cw; cb < SEQ; cb += 64) {
    {  // half A: PV(cb) from P[0]; scores(cb+32) -> P[1]
      const int nxt = cb + 32;
      if (nxt < SEQ) {
        if (cb + 64 < SEQ) {
#pragma unroll
          for (int h = 0; h < 2; h++) {
            kB0[h] = *(const bf16x8*)(Kl + (size_t)(cb + 64) * DH + h * 32);
            kB1[h] = *(const bf16x8*)(Kl + (size_t)(cb + 80) * DH + h * 32);
          }
        }
#pragma unroll
        for (int n = 0; n < 4; n++)
          vB[n] = *(const bf16x8*)(Vl + (size_t)(n * 16) * SEQ + nxt);
        const bool sp = (nxt == Cw + 32);  // keys local [32,64)
#pragma unroll
        for (int t = 0; t < 4; t++) {
          unsigned short* pw = &P[1][t][fr * PSTR + quad * 4];
          av_tile(kA0, bq[t], pw,
                  sp ? ((t < 2) ? FULLM : ((t == 2) ? DIAGM : ZEROM)) : FULLM, fr, quad);
          av_tile(kA1, bq[t], pw + 16,
                  sp ? ((t < 3) ? FULLM : DIAGM) : FULLM, fr, quad);
        }
      }
      bf16x8 pf[4];
#pragma unroll
      for (int t = 0; t < 4; t++)
        pf[t] = *(const bf16x8*)&P[0][t][fr * PSTR + quad * 8];
#pragma unroll
      for (int t = 0; t < 4; t++)
#pragma unroll
        for (int n = 0; n < 4; n++)
          zacc[t][n] = __builtin_amdgcn_mfma_f32_16x16x32_bf16(pf[t], vA[n], zacc[t][n], 0, 0, 0);
    }
    {  // half B: PV(cb+32) from P[1]; scores(cb+64) -> P[0]
      const int cb2 = cb + 32;  // always < SEQ (even trip count)
      const int nxt = cb2 + 32;
      if (nxt < SEQ) {
        if (cb2 + 64 < SEQ) {
#pragma unroll
          for (int h = 0; h < 2; h++) {
            kA0[h] = *(const bf16x8*)(Kl + (size_t)(cb2 + 64) * DH + h * 32);
            kA1[h] = *(const bf16x8*)(Kl + (size_t)(cb2 + 80) * DH + h * 32);
          }
        }
#pragma unroll
        for (int n = 0; n < 4; n++)
          vA[n] = *(const bf16x8*)(Vl + (size_t)(n * 16) * SEQ + nxt);
#pragma unroll
        for (int t = 0; t < 4; t++) {
          unsigned short* pw = &P[0][t][fr * PSTR + quad * 4];
          av_tile(kB0, bq[t], pw, FULLM, fr, quad);
          av_tile(kB1, bq[t], pw + 16, FULLM, fr, quad);
        }
      }
      bf16x8 pf[4];
#pragma unroll
      for (int t = 0; t < 4; t++)
        pf[t] = *(const bf16x8*)&P[1][t][fr * PSTR + quad * 8];
#pragma unroll
      for (int t = 0; t < 4; t++)
#pragma unroll
        for (int n = 0; n < 4; n++)
          zacc[t][n] = __builtin_amdgcn_mfma_f32_16x16x32_bf16(pf[t], vB[n], zacc[t][n], 0, 0, 0);
    }
  }

  const int b = head >> 4, a = head & 15;
#pragma unroll
  for (int t = 0; t < 4; t++)
#pragma unroll
    for (int n = 0; n < 4; n++)
#pragma unroll
      for (int i = 0; i < 4; i++) {
        const int C = Cw + t * 16 + quad * 4 + i;
        const int f = a * DH + n * 16 + fr;
        Z[((size_t)(b * SEQ + C) << 10) + f] = f2bf(zacc[t][n][i]);
      }
}

// ---------------- launch ----------------
extern "C" void kernel_launch(void* const* d_in, const int* in_sizes, int n_in,
                              void* d_out, int out_size, void* d_ws, size_t ws_size,
                              hipStream_t stream)
{
  const float* x  = (const float*)d_in[0];
  const float* wk = (const float*)d_in[1];
  const float* wq = (const float*)d_in[2];
  const float* wv = (const float*)d_in[3];
  const float* wo = (const float*)d_in[4];
  float* out = (float*)d_out;
  char* ws = (char*)d_ws;

  unsigned short* Xb  = (unsigned short*)(ws);            // 16 MB (aliased by Zb)
  unsigned short* Zb  = (unsigned short*)(ws);
  unsigned short* Kb  = (unsigned short*)(ws + 16777216);
  unsigned short* Qb  = (unsigned short*)(ws + 33554432);
  unsigned short* Vtb = (unsigned short*)(ws + 50331648);
  unsigned short* Wkb = (unsigned short*)(ws + 67108864);
  unsigned short* Wqb = (unsigned short*)(ws + 69206016);
  unsigned short* Wvb = (unsigned short*)(ws + 71303168);
  unsigned short* Wob = (unsigned short*)(ws + 73400320);
  float* Ls = (float*)(ws + 75497472);

  cvt_bf16<<<dim3(6144), 256, 0, stream>>>(x, wk, wq, wv, wo, Xb, Wkb, Wqb, Wvb, Wob);
  gemm_qkv<<<dim3(64, 12), 512, 0, stream>>>(Xb, Wkb, Wqb, Wvb, Kb, Qb, Vtb);
  attn_stats<<<dim3(128, 16), 64, 0, stream>>>(Kb, Qb, Ls);
  vscale<<<dim3(4096), 256, 0, stream>>>(Vtb, Ls);
  attn_av<<<dim3(128, 16), 64, 0, stream>>>(Kb, Qb, Vtb, Zb);
  gemm_out<<<dim3(64, 4), 512, 0, stream>>>(Zb, Wob, out);
}

// Round 6
// 266.100 us; speedup vs baseline: 1.4610x; 1.0735x over previous
//
#include <hip/hip_runtime.h>
#include <hip/hip_bf16.h>

// B=8, S=1024, H=16, D=64, E=1024. I/O fp32; internal bf16 MFMA.
// attn = softmax over QUERY axis C (per key row c) of tril(K Q^T)/8.
// Two-pass: l_c = sum_{C<=c} exp(s_cC/8); then z[C] = sum_{c>=C}
// (exp(s_cC/8)/l_c) * v_c, with 1/l folded into P (R14; vscale removed).
// R14: full revert to round-0 known-good forms after R9-R13 restructures
// all regressed (attn: 4-wave/32-chunk/XCD-remap; GEMM: 8-phase/3-buf).
// Deltas on top of round-0:
//  - vscale kernel removed; attn_av scales P by rcp(l[key]) post-exp
//    (2 float4 loads + 8 v_rcp per 32-key half-step, shared by 4 q-tiles).
//  - attn_av half-steps reordered PV-first: pf ds_reads + global loads
//    issue BEFORE the PV MFMAs and score tiles, so K/V/l loads have the
//    whole compute span to land and pf no longer waits on 8 ds_writes.

#define SEQ 1024
#define DH 64
#define NH 16
#define EMB 1024
#define SCALE 0.18033688011112042f  // 0.125 * log2(e)
#define PSTR 40                     // P row stride (u16), 80B = 16B-aligned

#define ZEROM 0
#define DIAGM 1
#define FULLM 2

typedef float f32x4 __attribute__((ext_vector_type(4)));
typedef __bf16 bf16x8 __attribute__((ext_vector_type(8)));
typedef unsigned short u16x8 __attribute__((ext_vector_type(8)));

__device__ __forceinline__ unsigned short f2bf(float f) {
  union { float f; unsigned int u; } v; v.f = f;
  unsigned int u = v.u;
  return (unsigned short)((u + 0x7fffu + ((u >> 16) & 1u)) >> 16);  // RNE
}
__device__ __forceinline__ unsigned short f2bf_fast(float f) {
  union { float f; unsigned int u; } v; v.f = f;
  return (unsigned short)((v.u + 0x8000u) >> 16);  // round-half-up (p>=0)
}
__device__ __forceinline__ float bf2f(unsigned short u) {
  union { unsigned int u; float f; } v; v.u = ((unsigned int)u) << 16; return v.f;
}

__device__ __forceinline__ u16x8 ld8_f32_bf16(const float* g) {
  const float4 a = *(const float4*)g;
  const float4 b = *(const float4*)(g + 4);
  u16x8 r;
  r[0] = f2bf(a.x); r[1] = f2bf(a.y); r[2] = f2bf(a.z); r[3] = f2bf(a.w);
  r[4] = f2bf(b.x); r[5] = f2bf(b.y); r[6] = f2bf(b.z); r[7] = f2bf(b.w);
  return r;
}

__device__ __forceinline__ void gl_lds16(const void* g, void* l) {
  __builtin_amdgcn_global_load_lds(
      (const __attribute__((address_space(1))) void*)g,
      (__attribute__((address_space(3))) void*)l, 16, 0, 0);
}

// ---------------- fp32 -> bf16 conversion of X and weights ----------------
__global__ __launch_bounds__(256) void cvt_bf16(
    const float* __restrict__ X, const float* __restrict__ Wk,
    const float* __restrict__ Wq, const float* __restrict__ Wv,
    const float* __restrict__ Wo,
    unsigned short* __restrict__ Xb, unsigned short* __restrict__ Wkb,
    unsigned short* __restrict__ Wqb, unsigned short* __restrict__ Wvb,
    unsigned short* __restrict__ Wob)
{
  const size_t i = ((size_t)blockIdx.x * 256 + threadIdx.x) * 8;
  const float* src; unsigned short* dst; size_t off;
  if (i < 8388608) { src = X; dst = Xb; off = i; }
  else {
    const size_t j = i - 8388608;
    const int sel = (int)(j >> 20); off = j & 1048575;
    src = (sel == 0) ? Wk : (sel == 1) ? Wq : (sel == 2) ? Wv : Wo;
    dst = (sel == 0) ? Wkb : (sel == 1) ? Wqb : (sel == 2) ? Wvb : Wob;
  }
  *(u16x8*)(dst + off) = ld8_f32_bf16(src + off);
}

// ---------------- GEMM core (BK=64, xor-swizzled LDS) ----------------
#define GEMM_BK64_BODY(Aptr, Bptr)                                              \
  f32x4 acc[4][4] = {};                                                         \
  const int srow = lane >> 3;                                                   \
  const int scol = (((lane & 7) ^ srow)) * 8;                                   \
  const unsigned short* Ag = (Aptr) + (size_t)(mt0 + wave * 32 + srow) * EMB + scol; \
  const unsigned short* Bg = (Bptr) + (size_t)(n0 + wave * 32 + srow) * EMB + scol;  \
  char* lA = (char*)As + wave * 4096;                                           \
  char* lB = (char*)Bs + wave * 4096;                                           \
  for (int k0 = 0; k0 < EMB; k0 += 64) {                                        \
    __syncthreads();                                                            \
    _Pragma("unroll")                                                           \
    for (int ch = 0; ch < 4; ch++) {                                            \
      gl_lds16(Ag + (size_t)ch * 8 * EMB + k0, lA + ch * 1024);                 \
      gl_lds16(Bg + (size_t)ch * 8 * EMB + k0, lB + ch * 1024);                 \
    }                                                                           \
    __syncthreads();                                                            \
    _Pragma("unroll")                                                           \
    for (int half = 0; half < 2; half++) {                                      \
      bf16x8 af[4], bfr[4];                                                     \
      _Pragma("unroll")                                                         \
      for (int t = 0; t < 4; t++) {                                             \
        const int ra = wm * 64 + t * 16 + fr;                                   \
        const int rb = wn * 64 + t * 16 + fr;                                   \
        af[t]  = *(const bf16x8*)&As[ra * 64 + (((half * 4 + quad) ^ (ra & 7)) * 8)]; \
        bfr[t] = *(const bf16x8*)&Bs[rb * 64 + (((half * 4 + quad) ^ (rb & 7)) * 8)]; \
      }                                                                         \
      _Pragma("unroll")                                                         \
      for (int i = 0; i < 4; i++)                                               \
        _Pragma("unroll")                                                       \
        for (int j = 0; j < 4; j++)                                             \
          acc[i][j] = __builtin_amdgcn_mfma_f32_16x16x32_bf16(af[i], bfr[j], acc[i][j], 0, 0, 0); \
    }                                                                           \
  }

// ---------------- GEMM: QKV projection ----------------
__global__ __launch_bounds__(256) void gemm_qkv(
    const unsigned short* __restrict__ X,
    const unsigned short* __restrict__ Wk,
    const unsigned short* __restrict__ Wq,
    const unsigned short* __restrict__ Wv,
    unsigned short* __restrict__ Kb,
    unsigned short* __restrict__ Qb,
    unsigned short* __restrict__ Vt)
{
  __shared__ __align__(16) unsigned short As[128 * 64];
  __shared__ __align__(16) unsigned short Bs[128 * 64];
  const int mt0 = blockIdx.x * 128;
  const int nt = blockIdx.y;
  const int sel = nt >> 3;
  const int n0 = (nt & 7) * 128;
  const unsigned short* W = (sel == 0) ? Wk : (sel == 1) ? Wq : Wv;

  const int tid = threadIdx.x;
  const int wave = tid >> 6, lane = tid & 63;
  const int wm = wave >> 1, wn = wave & 1;
  const int fr = lane & 15, quad = lane >> 4;

  GEMM_BK64_BODY(X, W)

  const int rl = quad * 4;
  if (sel < 2) {
    unsigned short* Dst = (sel == 0) ? Kb : Qb;
#pragma unroll
    for (int i = 0; i < 4; i++) {
      const int col = n0 + wn * 64 + i * 16 + fr;
      const int a = col >> 6, h = col & 63;
#pragma unroll
      for (int j = 0; j < 4; j++) {
        const int rowb = mt0 + wm * 64 + j * 16 + rl;
#pragma unroll
        for (int r = 0; r < 4; r++) {
          const int row = rowb + r;
          const int b = row >> 10, s = row & 1023;
          Dst[(size_t)((b * NH + a) * SEQ + s) * DH + h] = f2bf(acc[j][i][r]);
        }
      }
    }
  } else {
#pragma unroll
    for (int i = 0; i < 4; i++) {
      const int col = n0 + wn * 64 + i * 16 + fr;
      const int a = col >> 6, h = col & 63;
#pragma unroll
      for (int j = 0; j < 4; j++) {
        const int rowb = mt0 + wm * 64 + j * 16 + rl;
#pragma unroll
        for (int r = 0; r < 4; r++) {
          const int row = rowb + r;
          const int b = row >> 10, s = row & 1023;
          Vt[(size_t)((b * NH + a) * DH + h) * SEQ + s] = f2bf(acc[j][i][r]);
        }
      }
    }
  }
}

// ---------------- GEMM: output projection (bf16 in, fp32 out) ----------------
__global__ __launch_bounds__(256) void gemm_out(
    const unsigned short* __restrict__ Z,
    const unsigned short* __restrict__ Wo,
    float* __restrict__ Out)
{
  __shared__ __align__(16) unsigned short As[128 * 64];
  __shared__ __align__(16) unsigned short Bs[128 * 64];
  const int mt0 = blockIdx.x * 128;
  const int n0 = blockIdx.y * 128;

  const int tid = threadIdx.x;
  const int wave = tid >> 6, lane = tid & 63;
  const int wm = wave >> 1, wn = wave & 1;
  const int fr = lane & 15, quad = lane >> 4;

  GEMM_BK64_BODY(Z, Wo)

  const int rl = quad * 4;
#pragma unroll
  for (int i = 0; i < 4; i++) {
    const int col = n0 + wn * 64 + i * 16 + fr;
#pragma unroll
    for (int j = 0; j < 4; j++) {
      const int rowb = mt0 + wm * 64 + j * 16 + rl;
#pragma unroll
      for (int r = 0; r < 4; r++)
        Out[(size_t)(rowb + r) * EMB + col] = acc[j][i][r];
    }
  }
}

// ---------------- stats tile: accumulate exp into l4 ----------------
__device__ __forceinline__ void st_tile(
    const bf16x8* ka, const bf16x8* q, float* l4, int mode, int fr, int quad)
{
  f32x4 a = {0.f, 0.f, 0.f, 0.f};
  a = __builtin_amdgcn_mfma_f32_16x16x32_bf16(ka[0], q[0], a, 0, 0, 0);
  a = __builtin_amdgcn_mfma_f32_16x16x32_bf16(ka[1], q[1], a, 0, 0, 0);
#pragma unroll
  for (int i = 0; i < 4; i++) {
    const float e = exp2f(a[i] * SCALE);
    l4[i] += (mode == FULLM || fr <= quad * 4 + i) ? e : 0.f;
  }
}

// ---------------- Pass 1: l_c = sum_{C<=c} exp(s_cC/8) ----------------
// 64 c-rows per wave. grid (128 heads, 16 chunks), 64 thr. y=0 -> heaviest.
__global__ __launch_bounds__(64, 4) void attn_stats(
    const unsigned short* __restrict__ Kb, const unsigned short* __restrict__ Qb,
    float* __restrict__ Ls)
{
  const int head = blockIdx.x;
  const int j = 15 - (int)blockIdx.y;
  const int cw = j * 64;
  const int lane = threadIdx.x & 63;
  const int fr = lane & 15, quad = lane >> 4;
  const unsigned short* Kh = Kb + (size_t)head * (SEQ * DH);
  const unsigned short* Qh = Qb + (size_t)head * (SEQ * DH);
  const unsigned short* Kl = Kh + (size_t)fr * DH + quad * 8;
  const unsigned short* Ql = Qh + (size_t)fr * DH + quad * 8;

  bf16x8 ka[4][2];
#pragma unroll
  for (int s = 0; s < 4; s++)
#pragma unroll
    for (int h = 0; h < 2; h++)
      ka[s][h] = *(const bf16x8*)(Kl + (size_t)(cw + s * 16) * DH + h * 32);

  float l[4][4] = {};

  // main loop: full tiles, unroll-2 ping-pong (trip count 2j is even)
  bf16x8 qA0[2], qA1[2], qB0[2], qB1[2];
  if (cw > 0) {
#pragma unroll
    for (int h = 0; h < 2; h++) {
      qA0[h] = *(const bf16x8*)(Ql + h * 32);
      qA1[h] = *(const bf16x8*)(Ql + (size_t)16 * DH + h * 32);
    }
  }
  for (int Ct = 0; Ct < cw; Ct += 64) {
    {  // half A: queries [Ct, Ct+32)
      const int nq = Ct + 32;
      if (nq < cw) {
#pragma unroll
        for (int h = 0; h < 2; h++) {
          qB0[h] = *(const bf16x8*)(Ql + (size_t)nq * DH + h * 32);
          qB1[h] = *(const bf16x8*)(Ql + (size_t)(nq + 16) * DH + h * 32);
        }
      }
#pragma unroll
      for (int s = 0; s < 4; s++) {
        st_tile(ka[s], qA0, l[s], FULLM, fr, quad);
        st_tile(ka[s], qA1, l[s], FULLM, fr, quad);
      }
    }
    {  // half B: queries [Ct+32, Ct+64)
      const int cq = Ct + 32;
      if (cq < cw) {
        const int nq = cq + 32;
        if (nq < cw) {
#pragma unroll
          for (int h = 0; h < 2; h++) {
            qA0[h] = *(const bf16x8*)(Ql + (size_t)nq * DH + h * 32);
            qA1[h] = *(const bf16x8*)(Ql + (size_t)(nq + 16) * DH + h * 32);
          }
        }
#pragma unroll
        for (int s = 0; s < 4; s++) {
          st_tile(ka[s], qB0, l[s], FULLM, fr, quad);
          st_tile(ka[s], qB1, l[s], FULLM, fr, quad);
        }
      }
    }
  }

  {  // peeled Ct = cw (queries local [0,32))
    bf16x8 q0[2], q1[2];
#pragma unroll
    for (int h = 0; h < 2; h++) {
      q0[h] = *(const bf16x8*)(Ql + (size_t)cw * DH + h * 32);
      q1[h] = *(const bf16x8*)(Ql + (size_t)(cw + 16) * DH + h * 32);
    }
    st_tile(ka[0], q0, l[0], DIAGM, fr, quad);
    st_tile(ka[1], q0, l[1], FULLM, fr, quad);
    st_tile(ka[2], q0, l[2], FULLM, fr, quad);
    st_tile(ka[3], q0, l[3], FULLM, fr, quad);
    st_tile(ka[1], q1, l[1], DIAGM, fr, quad);
    st_tile(ka[2], q1, l[2], FULLM, fr, quad);
    st_tile(ka[3], q1, l[3], FULLM, fr, quad);
  }
  {  // peeled Ct = cw+32 (queries local [32,64))
    bf16x8 q0[2], q1[2];
#pragma unroll
    for (int h = 0; h < 2; h++) {
      q0[h] = *(const bf16x8*)(Ql + (size_t)(cw + 32) * DH + h * 32);
      q1[h] = *(const bf16x8*)(Ql + (size_t)(cw + 48) * DH + h * 32);
    }
    st_tile(ka[2], q0, l[2], DIAGM, fr, quad);
    st_tile(ka[3], q0, l[3], FULLM, fr, quad);
    st_tile(ka[3], q1, l[3], DIAGM, fr, quad);
  }

#pragma unroll
  for (int s = 0; s < 4; s++)
#pragma unroll
    for (int i = 0; i < 4; i++) {
      float v = l[s][i];
      v += __shfl_xor(v, 1); v += __shfl_xor(v, 2);
      v += __shfl_xor(v, 4); v += __shfl_xor(v, 8);
      if (fr == 0) Ls[head * SEQ + cw + s * 16 + quad * 4 + i] = v;
    }
}

// ------- load 2x float4 of l and reciprocate (keys kb..kb+31) -------
__device__ __forceinline__ void ldrl(const float* Lh, int kb, int quad,
                                     f32x4* r0, f32x4* r1)
{
  const float4 a = *(const float4*)(Lh + kb + quad * 4);
  const float4 b = *(const float4*)(Lh + kb + 16 + quad * 4);
  (*r0)[0] = __builtin_amdgcn_rcpf(a.x); (*r0)[1] = __builtin_amdgcn_rcpf(a.y);
  (*r0)[2] = __builtin_amdgcn_rcpf(a.z); (*r0)[3] = __builtin_amdgcn_rcpf(a.w);
  (*r1)[0] = __builtin_amdgcn_rcpf(b.x); (*r1)[1] = __builtin_amdgcn_rcpf(b.y);
  (*r1)[2] = __builtin_amdgcn_rcpf(b.z); (*r1)[3] = __builtin_amdgcn_rcpf(b.w);
}

// -------- av score tile -> LDS, scaled by rcp(l[key]) (R14 fold) --------
__device__ __forceinline__ void av_tile_s(
    const bf16x8* ka, const bf16x8* bq, const f32x4 rl,
    unsigned short* __restrict__ pw, int mode, int fr, int quad)
{
  if (mode == ZEROM) { *(uint2*)pw = make_uint2(0u, 0u); return; }
  f32x4 acc = {0.f, 0.f, 0.f, 0.f};
  acc = __builtin_amdgcn_mfma_f32_16x16x32_bf16(ka[0], bq[0], acc, 0, 0, 0);
  acc = __builtin_amdgcn_mfma_f32_16x16x32_bf16(ka[1], bq[1], acc, 0, 0, 0);
  unsigned short us[4];
#pragma unroll
  for (int i = 0; i < 4; i++) {
    float p = exp2f(acc[i] * SCALE) * rl[i];   // row = key = quad*4+i
    if (mode == DIAGM && (quad * 4 + i < fr)) p = 0.f;
    us[i] = f2bf_fast(p);
  }
  uint2 pk;
  pk.x = (unsigned)us[0] | ((unsigned)us[1] << 16);
  pk.y = (unsigned)us[2] | ((unsigned)us[3] << 16);
  *(uint2*)pw = pk;
}

// ---------------- Pass 2: z = sum_c (P_cC / l_c) v_c ----------------
// 64 C-rows per wave, unroll-2 ping-pong, no barriers. PV-first ordering:
// pf ds_reads + l/K/V global loads issue before PV MFMAs; score tiles
// (MFMA+exp+scale+ds_write) follow. grid (128 heads, 16 chunks), 64 thr.
__global__ __launch_bounds__(64, 2) void attn_av(
    const unsigned short* __restrict__ Kb, const unsigned short* __restrict__ Qb,
    const unsigned short* __restrict__ Vt, const float* __restrict__ Ls,
    unsigned short* __restrict__ Z)
{
  __shared__ __align__(16) unsigned short P[2][4][16 * PSTR];
  const int head = blockIdx.x;
  const int lane = threadIdx.x & 63;
  const int fr = lane & 15, quad = lane >> 4;
  const unsigned short* Kh = Kb + (size_t)head * (SEQ * DH);
  const unsigned short* Qh = Qb + (size_t)head * (SEQ * DH);
  const unsigned short* Vh = Vt + (size_t)head * (SEQ * DH);
  const float* Lh = Ls + (size_t)head * SEQ;
  const unsigned short* Kl = Kh + (size_t)fr * DH + quad * 8;
  const unsigned short* Ql = Qh + (size_t)fr * DH + quad * 8;
  const unsigned short* Vl = Vh + (size_t)fr * SEQ + quad * 8;
  const int Cw = blockIdx.y * 64;

  bf16x8 bq[4][2];
#pragma unroll
  for (int t = 0; t < 4; t++)
#pragma unroll
    for (int h = 0; h < 2; h++)
      bq[t][h] = *(const bf16x8*)(Ql + (size_t)(Cw + t * 16) * DH + h * 32);

  f32x4 zacc[4][4] = {};
  bf16x8 kA0[2], kA1[2], kB0[2], kB1[2], vA[4], vB[4];

  {  // prologue: scores(Cw) -> P[0]  (keys local [0,32))
    f32x4 rl0, rl1;
    ldrl(Lh, Cw, quad, &rl0, &rl1);
    bf16x8 kp0[2], kp1[2];
#pragma unroll
    for (int h = 0; h < 2; h++) {
      kp0[h] = *(const bf16x8*)(Kl + (size_t)Cw * DH + h * 32);
      kp1[h] = *(const bf16x8*)(Kl + (size_t)(Cw + 16) * DH + h * 32);
    }
#pragma unroll
    for (int t = 0; t < 4; t++) {
      unsigned short* pw = &P[0][t][fr * PSTR + quad * 4];
      av_tile_s(kp0, bq[t], rl0, pw, (t == 0) ? DIAGM : ZEROM, fr, quad);
      av_tile_s(kp1, bq[t], rl1, pw + 16,
                (t == 0) ? FULLM : ((t == 1) ? DIAGM : ZEROM), fr, quad);
    }
  }
  if (Cw + 32 < SEQ) {  // K for first half-A scores
#pragma unroll
    for (int h = 0; h < 2; h++) {
      kA0[h] = *(const bf16x8*)(Kl + (size_t)(Cw + 32) * DH + h * 32);
      kA1[h] = *(const bf16x8*)(Kl + (size_t)(Cw + 48) * DH + h * 32);
    }
  }
#pragma unroll
  for (int n = 0; n < 4; n++)  // V(Cw)
    vA[n] = *(const bf16x8*)(Vl + (size_t)(n * 16) * SEQ + Cw);

  for (int cb = Cw; cb < SEQ; cb += 64) {
    {  // half A: PV(cb) from P[0]; scores keys [cb+32,cb+64) -> P[1]
      const int nxt = cb + 32;
      bf16x8 pf[4];
#pragma unroll
      for (int t = 0; t < 4; t++)
        pf[t] = *(const bf16x8*)&P[0][t][fr * PSTR + quad * 8];
      f32x4 rl0, rl1;
      if (nxt < SEQ) {
        ldrl(Lh, nxt, quad, &rl0, &rl1);
        if (cb + 64 < SEQ) {
#pragma unroll
          for (int h = 0; h < 2; h++) {
            kB0[h] = *(const bf16x8*)(Kl + (size_t)(cb + 64) * DH + h * 32);
            kB1[h] = *(const bf16x8*)(Kl + (size_t)(cb + 80) * DH + h * 32);
          }
        }
#pragma unroll
        for (int n = 0; n < 4; n++)
          vB[n] = *(const bf16x8*)(Vl + (size_t)(n * 16) * SEQ + nxt);
      }
#pragma unroll
      for (int t = 0; t < 4; t++)
#pragma unroll
        for (int n = 0; n < 4; n++)
          zacc[t][n] = __builtin_amdgcn_mfma_f32_16x16x32_bf16(pf[t], vA[n], zacc[t][n], 0, 0, 0);
      if (nxt < SEQ) {
        const bool sp = (nxt == Cw + 32);  // keys local [32,64)
#pragma unroll
        for (int t = 0; t < 4; t++) {
          unsigned short* pw = &P[1][t][fr * PSTR + quad * 4];
          av_tile_s(kA0, bq[t], rl0, pw,
                    sp ? ((t < 2) ? FULLM : ((t == 2) ? DIAGM : ZEROM)) : FULLM, fr, quad);
          av_tile_s(kA1, bq[t], rl1, pw + 16,
                    sp ? ((t < 3) ? FULLM : DIAGM) : FULLM, fr, quad);
        }
      }
    }
    {  // half B: PV(cb+32) from P[1]; scores keys [cb+64,cb+96) -> P[0]
      const int cb2 = cb + 32;  // always < SEQ (even trip count)
      const int nxt = cb2 + 32;
      bf16x8 pf[4];
#pragma unroll
      for (int t = 0; t < 4; t++)
        pf[t] = *(const bf16x8*)&P[1][t][fr * PSTR + quad * 8];
      f32x4 rl0, rl1;
      if (nxt < SEQ) {
        ldrl(Lh, nxt, quad, &rl0, &rl1);
        if (cb2 + 64 < SEQ) {
#pragma unroll
          for (int h = 0; h < 2; h++) {
            kA0[h] = *(const bf16x8*)(Kl + (size_t)(cb2 + 64) * DH + h * 32);
            kA1[h] = *(const bf16x8*)(Kl + (size_t)(cb2 + 80) * DH + h * 32);
          }
        }
#pragma unroll
        for (int n = 0; n < 4; n++)
          vA[n] = *(const bf16x8*)(Vl + (size_t)(n * 16) * SEQ + nxt);
      }
#pragma unroll
      for (int t = 0; t < 4; t++)
#pragma unroll
        for (int n = 0; n < 4; n++)
          zacc[t][n] = __builtin_amdgcn_mfma_f32_16x16x32_bf16(pf[t], vB[n], zacc[t][n], 0, 0, 0);
      if (nxt < SEQ) {
#pragma unroll
        for (int t = 0; t < 4; t++) {
          unsigned short* pw = &P[0][t][fr * PSTR + quad * 4];
          av_tile_s(kB0, bq[t], rl0, pw, FULLM, fr, quad);
          av_tile_s(kB1, bq[t], rl1, pw + 16, FULLM, fr, quad);
        }
      }
    }
  }

  const int b = head >> 4, a = head & 15;
#pragma unroll
  for (int t = 0; t < 4; t++)
#pragma unroll
    for (int n = 0; n < 4; n++)
#pragma unroll
      for (int i = 0; i < 4; i++) {
        const int C = Cw + t * 16 + quad * 4 + i;
        const int f = a * DH + n * 16 + fr;
        Z[((size_t)(b * SEQ + C) << 10) + f] = f2bf(zacc[t][n][i]);
      }
}

// ---------------- launch ----------------
extern "C" void kernel_launch(void* const* d_in, const int* in_sizes, int n_in,
                              void* d_out, int out_size, void* d_ws, size_t ws_size,
                              hipStream_t stream)
{
  const float* x  = (const float*)d_in[0];
  const float* wk = (const float*)d_in[1];
  const float* wq = (const float*)d_in[2];
  const float* wv = (const float*)d_in[3];
  const float* wo = (const float*)d_in[4];
  float* out = (float*)d_out;
  char* ws = (char*)d_ws;

  unsigned short* Xb  = (unsigned short*)(ws);            // 16 MB (aliased by Zb)
  unsigned short* Zb  = (unsigned short*)(ws);
  unsigned short* Kb  = (unsigned short*)(ws + 16777216);
  unsigned short* Qb  = (unsigned short*)(ws + 33554432);
  unsigned short* Vtb = (unsigned short*)(ws + 50331648);
  unsigned short* Wkb = (unsigned short*)(ws + 67108864);
  unsigned short* Wqb = (unsigned short*)(ws + 69206016);
  unsigned short* Wvb = (unsigned short*)(ws + 71303168);
  unsigned short* Wob = (unsigned short*)(ws + 73400320);
  float* Ls = (float*)(ws + 75497472);

  cvt_bf16<<<dim3(6144), 256, 0, stream>>>(x, wk, wq, wv, wo, Xb, Wkb, Wqb, Wvb, Wob);
  gemm_qkv<<<dim3(64, 24), 256, 0, stream>>>(Xb, Wkb, Wqb, Wvb, Kb, Qb, Vtb);
  attn_stats<<<dim3(128, 16), 64, 0, stream>>>(Kb, Qb, Ls);
  attn_av<<<dim3(128, 16), 64, 0, stream>>>(Kb, Qb, Vtb, Ls, Zb);
  gemm_out<<<dim3(64, 8), 256, 0, stream>>>(Zb, Wob, out);
}